// Round 7
// baseline (520.062 us; speedup 1.0000x reference)
//
#include <hip/hip_runtime.h>
#include <cstdint>
#include <cstddef>

#define S_ 512
#define B_ 16
#define H_ 8
#define D_ 64
#define E_ 512
#define FFN_ 2048
#define R_ (S_*B_)          // 8192 rows (s*B+b)
#define EPSF 1e-6f
#define PROJ_M 0.99999f     // 1 - 1e-5

typedef __attribute__((ext_vector_type(8))) short bf16x8;
typedef __attribute__((ext_vector_type(4))) float f32x4;
typedef __attribute__((ext_vector_type(2))) unsigned int u32x2;

// ---------- helpers ----------
__device__ __forceinline__ float bf2f(uint32_t u){
  union{uint32_t i; float f;} c; c.i = u<<16; return c.f;
}
__device__ __forceinline__ uint16_t f2bf(float f){
  union{float f; uint32_t i;} c; c.f = f;
  return (uint16_t)((c.i + 0x7FFFu + ((c.i>>16)&1u))>>16);
}
__device__ __forceinline__ void unpack8(uint4 u, float* f){
  f[0]=bf2f(u.x&0xFFFFu); f[1]=bf2f(u.x>>16);
  f[2]=bf2f(u.y&0xFFFFu); f[3]=bf2f(u.y>>16);
  f[4]=bf2f(u.z&0xFFFFu); f[5]=bf2f(u.z>>16);
  f[6]=bf2f(u.w&0xFFFFu); f[7]=bf2f(u.w>>16);
}
__device__ __forceinline__ uint4 pack8(const float* f){
  uint4 u;
  u.x = (uint32_t)f2bf(f[0]) | ((uint32_t)f2bf(f[1])<<16);
  u.y = (uint32_t)f2bf(f[2]) | ((uint32_t)f2bf(f[3])<<16);
  u.z = (uint32_t)f2bf(f[4]) | ((uint32_t)f2bf(f[5])<<16);
  u.w = (uint32_t)f2bf(f[6]) | ((uint32_t)f2bf(f[7])<<16);
  return u;
}
__device__ __forceinline__ float artanh_c(float x){
  return (x >= 0.99999994f) ? 8.4056215f : atanhf(x);
}
__device__ __forceinline__ float wave_sum(float x){
  #pragma unroll
  for(int o=32;o>=1;o>>=1) x += __shfl_xor(x,o);
  return x;
}
__device__ __forceinline__ float halfsum32(float x){
  #pragma unroll
  for(int o=16;o>=1;o>>=1) x += __shfl_xor(x,o);
  return x;
}
__device__ __forceinline__ float block_sum(float x, float* sb){
  x = wave_sum(x);
  const int w = threadIdx.x >> 6;
  __syncthreads();
  if((threadIdx.x & 63)==0) sb[w] = x;
  __syncthreads();
  return sb[0]+sb[1]+sb[2]+sb[3];
}
// async global->LDS, 16B per lane; LDS dest = wave-uniform base + lane*16
__device__ __forceinline__ void gl_lds16(const void* g, void* l){
  __builtin_amdgcn_global_load_lds(
    (const __attribute__((address_space(1))) void*)(uintptr_t)g,
    (__attribute__((address_space(3))) void*)(uint32_t)(uintptr_t)l, 16, 0, 0);
}
__device__ __forceinline__ uint32_t cvtpk(float a, float b){
  uint32_t r;
  asm("v_cvt_pk_bf16_f32 %0, %1, %2" : "=v"(r) : "v"(a), "v"(b));
  return r;
}
template<int OFF>
__device__ __forceinline__ u32x2 trrd(uint32_t addr){
  u32x2 r;
  asm volatile("ds_read_b64_tr_b16 %0, %1 offset:%2" : "=v"(r) : "v"(addr), "n"(OFF));
  return r;
}
__device__ __forceinline__ bf16x8 vcomb(u32x2 a, u32x2 b){
  union{ uint32_t u[4]; bf16x8 v; } c;
  c.u[0]=a[0]; c.u[1]=a[1]; c.u[2]=b[0]; c.u[3]=b[1];
  return c.v;
}
template<int N> __device__ __forceinline__ void vwait(){
  if constexpr(N==0)      asm volatile("s_waitcnt vmcnt(0)" ::: "memory");
  else if constexpr(N==2) asm volatile("s_waitcnt vmcnt(2)" ::: "memory");
  else if constexpr(N==3) asm volatile("s_waitcnt vmcnt(3)" ::: "memory");
  else if constexpr(N==4) asm volatile("s_waitcnt vmcnt(4)" ::: "memory");
  else                    asm volatile("s_waitcnt vmcnt(6)" ::: "memory");
}

// ---------- all weights fp32 -> bf16 (both experts), one launch ----------
__global__ __launch_bounds__(256) void cvt_all(
  const float* __restrict__ Wq, const float* __restrict__ Wk,
  const float* __restrict__ Wv, const float* __restrict__ Wo,
  const float* __restrict__ W1, const float* __restrict__ W2,
  uint16_t* __restrict__ dst)
{
  int i4 = blockIdx.x*256 + threadIdx.x;   // 4-elem units, total 1572864
  int e = 0;
  if(i4 >= 786432){ e = 1; i4 -= 786432; }
  const int r = i4;
  const float* s;
  if(r < 65536)        s = Wq + (size_t)(r)*4        + (size_t)e*262144;
  else if(r < 131072)  s = Wk + (size_t)(r-65536)*4  + (size_t)e*262144;
  else if(r < 196608)  s = Wv + (size_t)(r-131072)*4 + (size_t)e*262144;
  else if(r < 262144)  s = Wo + (size_t)(r-196608)*4 + (size_t)e*262144;
  else if(r < 524288)  s = W1 + (size_t)(r-262144)*4 + (size_t)e*1048576;
  else                 s = W2 + (size_t)(r-524288)*4 + (size_t)e*1048576;
  const float4 f = *(const float4*)s;
  uint2 o;
  o.x = (uint32_t)f2bf(f.x) | ((uint32_t)f2bf(f.y)<<16);
  o.y = (uint32_t)f2bf(f.z) | ((uint32_t)f2bf(f.w)<<16);
  *(uint2*)(dst + (size_t)e*3145728 + (size_t)r*4) = o;
}

// ---------- expmap0 of all 6 expert-1 biases ----------
__global__ __launch_bounds__(256) void expmap_all(
  const float* __restrict__ bq, const float* __restrict__ bk,
  const float* __restrict__ bv, const float* __restrict__ bo,
  const float* __restrict__ b1, const float* __restrict__ b2,
  float* __restrict__ YV)
{
  __shared__ float sb[4];
  const int id = blockIdx.x, t = threadIdx.x;
  const float* src; float* dst; int C;
  if(id==0){ src=bq+E_;   dst=YV+0;    C=E_; }
  else if(id==1){ src=bk+E_;   dst=YV+513;  C=E_; }
  else if(id==2){ src=bv+E_;   dst=YV+1026; C=E_; }
  else if(id==3){ src=bo+E_;   dst=YV+1539; C=E_; }
  else if(id==4){ src=b1+FFN_; dst=YV+2052; C=FFN_; }
  else          { src=b2+E_;   dst=YV+4101; C=E_; }
  const int npc = C >> 8;
  float v[8]; float s2 = 0.f;
  for(int i=0;i<npc;i++){ v[i] = src[t+256*i]; s2 += v[i]*v[i]; }
  s2 = block_sum(s2, sb);
  const float n = sqrtf(s2 + 1e-15f);
  const float th = tanhf(n);
  const float sc = th/n;
  for(int i=0;i<npc;i++) dst[t+256*i] = v[i]*sc;
  if(t==0) dst[C] = th*th;
}

// ---------- plain layernorm (euclid), row=512, fp32 in -> bf16 ----------
__global__ __launch_bounds__(256) void ln_k(const float* __restrict__ x,
  const float* __restrict__ g, const float* __restrict__ b, uint16_t* __restrict__ out)
{
  __shared__ float sb[4];
  const int row = blockIdx.x, t = threadIdx.x;
  const size_t base = (size_t)row*E_;
  float v0 = x[base+t], v1 = x[base+t+256];
  const float mu  = block_sum(v0+v1, sb) * (1.f/E_);
  const float d0 = v0-mu, d1 = v1-mu;
  const float var = block_sum(d0*d0+d1*d1, sb) * (1.f/E_);
  const float rs = 1.f/sqrtf(var + 1e-5f);
  out[base+t]     = f2bf(d0*rs*g[t] + b[t]);
  out[base+t+256] = f2bf(d1*rs*g[t+256] + b[t+256]);
}

// ---------- hyp: expmap0(LN(x)) [+projx]  (logmap0 scale cancels in LN) ----------
__global__ __launch_bounds__(256) void hyp_lnexp(const float* __restrict__ x,
  const float* __restrict__ g, const float* __restrict__ b,
  uint16_t* __restrict__ out, float* __restrict__ nout, int do_projx)
{
  __shared__ float sb[4];
  const int row = blockIdx.x, t = threadIdx.x;
  const size_t base = (size_t)row*E_;
  float v0 = x[base+t], v1 = x[base+t+256];
  const float mu  = block_sum(v0+v1, sb) * (1.f/E_);
  const float d0 = v0-mu, d1 = v1-mu;
  const float var = block_sum(d0*d0+d1*d1, sb) * (1.f/E_);
  const float rs = 1.f/sqrtf(var + 1e-5f);
  float t0 = d0*rs*g[t] + b[t];
  float t1 = d1*rs*g[t+256] + b[t+256];
  const float n2s = block_sum(t0*t0+t1*t1, sb);
  const float n2 = sqrtf(n2s + 1e-15f);
  const float nh = tanhf(n2);
  const float scl = nh/n2;
  t0 *= scl; t1 *= scl;
  float nrm = nh;
  if(do_projx && nrm > PROJ_M){ const float s = PROJ_M/nrm; t0*=s; t1*=s; nrm = PROJ_M; }
  out[base+t] = f2bf(t0); out[base+t+256] = f2bf(t1);
  if(t==0) nout[row] = nrm;
}

// ---------- per-head squared norms of euclid Q,K (layout [b*8+h][s]) ----------
__global__ __launch_bounds__(256) void qk_norms(
  const uint16_t* __restrict__ Qb, const uint16_t* __restrict__ Kb,
  float* __restrict__ qn, float* __restrict__ kn)
{
  const int w = threadIdx.x >> 6, l = threadIdx.x & 63;
  const int row = blockIdx.x*4 + w;
  const int s = row >> 4, b = row & 15;
  const size_t base = (size_t)row*E_ + l*8;
  {
    uint4 u = *(const uint4*)(Qb + base);
    float f[8]; unpack8(u, f);
    float ss = 0.f;
    #pragma unroll
    for(int i=0;i<8;i++) ss += f[i]*f[i];
    ss += __shfl_xor(ss,1); ss += __shfl_xor(ss,2); ss += __shfl_xor(ss,4);
    if((l&7)==0) qn[((b<<3) + (l>>3))*512 + s] = ss;
  }
  {
    uint4 u = *(const uint4*)(Kb + base);
    float f[8]; unpack8(u, f);
    float ss = 0.f;
    #pragma unroll
    for(int i=0;i<8;i++) ss += f[i]*f[i];
    ss += __shfl_xor(ss,1); ss += __shfl_xor(ss,2); ss += __shfl_xor(ss,4);
    if((l&7)==0) kn[((b<<3) + (l>>3))*512 + s] = ss;
  }
}

// ---------- man_linear epilogue (generic): flags 1 relu; 8 projx on midpoint ----------
template<int NPC>
__global__ __launch_bounds__(256) void man_epi(
  const uint16_t* __restrict__ mxb, const float* __restrict__ nxbuf,
  const float* __restrict__ y, uint16_t* __restrict__ outb,
  float* __restrict__ nout,
  const float* __restrict__ midres, float* __restrict__ midout, int flags)
{
  constexpr int C = NPC*256;
  __shared__ float sb[4];
  const int row = blockIdx.x, t = threadIdx.x;
  const size_t base = (size_t)row*C + (size_t)t*NPC;
  float v[NPC], yv[NPC];
  if(NPC==2){
    const uint32_t u = *(const uint32_t*)(mxb + base);
    v[0] = bf2f(u & 0xFFFFu); v[1] = bf2f(u >> 16);
  } else {
    const uint4 u = *(const uint4*)(mxb + base);
    unpack8(u, v);
  }
  float s2 = 0.f;
  #pragma unroll
  for(int i=0;i<NPC;i++){ yv[i] = y[t*NPC + i]; s2 += v[i]*v[i]; }
  s2 = block_sum(s2, sb);
  const float nmx = sqrtf(s2 + 1e-15f);
  const float nx  = nxbuf[row];
  const float sc  = tanhf(nmx/nx * artanh_c(nx));
  const bool ok   = (nmx > 1e-7f);
  const float fmul = ok ? (sc/nmx) : 0.f;
  const float x2   = ok ? sc*sc : 0.f;
  float xy = 0.f;
  #pragma unroll
  for(int i=0;i<NPC;i++){ v[i] *= fmul; xy += v[i]*yv[i]; }
  xy = block_sum(xy, sb);
  const float y2 = y[C];
  const float aa = 1.f + 2.f*xy + y2;
  const float bb = 1.f - x2;
  const float iden = 1.f/fmaxf(1.f + 2.f*xy + x2*y2, EPSF);
  const float num2 = aa*aa*x2 + 2.f*aa*bb*xy + bb*bb*y2;
  const float nz = sqrtf(num2*iden*iden + 1e-15f);
  const float ps = (nz > PROJ_M) ? (PROJ_M/nz) : 1.f;
  float nfin = (nz > PROJ_M) ? PROJ_M : nz;
  #pragma unroll
  for(int i=0;i<NPC;i++) v[i] = (aa*v[i] + bb*yv[i]) * iden * ps;
  if(flags & 1){
    float rs = 0.f;
    #pragma unroll
    for(int i=0;i<NPC;i++){ v[i] = fmaxf(v[i], 0.f); rs += v[i]*v[i]; }
    rs = block_sum(rs, sb);
    nfin = sqrtf(rs + 1e-15f);
  }
  if(midres){
    float bv2[NPC];
    float pb = 0.f, pab = 0.f;
    #pragma unroll
    for(int i=0;i<NPC;i++){ bv2[i] = midres[base + i]; pb += bv2[i]*bv2[i]; pab += v[i]*bv2[i]; }
    const float sa  = nfin*nfin;
    const float sbb = block_sum(pb, sb);
    const float sab = block_sum(pab, sb);
    const float l1 = 2.f/fmaxf(1.f - sa,  EPSF);
    const float l2 = 2.f/fmaxf(1.f - sbb, EPSF);
    const float idn = 1.f/fmaxf(l1 + l2 - 2.f, EPSF);
    const float nt2 = (l1*l1*sa + 2.f*l1*l2*sab + l2*l2*sbb)*idn*idn;
    const float nt = sqrtf(nt2 + 1e-15f);
    const float sfin = tanhf(0.5f*artanh_c(nt));
    float scm = sfin/nt;
    if((flags & 8) && sfin > PROJ_M) scm *= PROJ_M/sfin;
    #pragma unroll
    for(int i=0;i<NPC;i++) midout[base + i] = (v[i]*l1 + bv2[i]*l2)*idn*scm;
  } else {
    if(NPC==2){
      uint32_t u = (uint32_t)f2bf(v[0]) | ((uint32_t)f2bf(v[1])<<16);
      *(uint32_t*)(outb + base) = u;
    } else {
      *(uint4*)(outb + base) = pack8(v);
    }
    if(nout && t==0) nout[row] = nfin;
  }
}

// ---------- fused hyp q/k/v man_linear epilogue: per-head projx, lam fold for v ----------
__global__ __launch_bounds__(256) void man_epi_qkv(
  const uint16_t* __restrict__ mxb, const float* __restrict__ nxbuf,
  const float* __restrict__ YV, uint16_t* __restrict__ qkv,
  float* __restrict__ qnG, float* __restrict__ knG, float* __restrict__ lamG)
{
  __shared__ float sb[4];
  const int sel = blockIdx.y;
  const int row = blockIdx.x, t = threadIdx.x;
  const float* y = YV + sel*513;
  float v[2], yv[2];
  {
    const uint32_t u = *(const uint32_t*)(mxb + (size_t)row*1536 + sel*512 + t*2);
    v[0] = bf2f(u & 0xFFFFu); v[1] = bf2f(u >> 16);
  }
  float s2 = 0.f;
  #pragma unroll
  for(int i=0;i<2;i++){ yv[i] = y[t*2 + i]; s2 += v[i]*v[i]; }
  s2 = block_sum(s2, sb);
  const float nmx = sqrtf(s2 + 1e-15f);
  const float nx  = nxbuf[row];
  const float sc  = tanhf(nmx/nx * artanh_c(nx));
  const bool ok   = (nmx > 1e-7f);
  const float fmul = ok ? (sc/nmx) : 0.f;
  const float x2   = ok ? sc*sc : 0.f;
  float xy = 0.f;
  #pragma unroll
  for(int i=0;i<2;i++){ v[i] *= fmul; xy += v[i]*yv[i]; }
  xy = block_sum(xy, sb);
  const float y2 = y[512];
  const float aa = 1.f + 2.f*xy + y2;
  const float bb = 1.f - x2;
  const float iden = 1.f/fmaxf(1.f + 2.f*xy + x2*y2, EPSF);
  const float num2 = aa*aa*x2 + 2.f*aa*bb*xy + bb*bb*y2;
  const float nz = sqrtf(num2*iden*iden + 1e-15f);
  const float ps = (nz > PROJ_M) ? (PROJ_M/nz) : 1.f;
  #pragma unroll
  for(int i=0;i<2;i++) v[i] = (aa*v[i] + bb*yv[i]) * iden * ps;
  // per-head projx (+ lambda)
  float hs = halfsum32(v[0]*v[0] + v[1]*v[1]);
  float nh = sqrtf(hs + 1e-15f);
  float phs = 1.f;
  if(nh > PROJ_M){ phs = PROJ_M/nh; nh = PROJ_M; }
  v[0] *= phs; v[1] *= phs;
  const float nh2 = nh*nh;
  const float lam = 2.f/fmaxf(1.f - nh2, EPSF);
  if(sel==2){ v[0] *= lam; v[1] *= lam; }
  if((t & 31) == 0){
    const int s = row >> 4, b = row & 15;
    const int idx = ((b<<3) + (t>>5))*512 + s;
    if(sel==0) qnG[idx] = nh2;
    else if(sel==1) knG[idx] = nh2;
    else lamG[idx] = lam;
  }
  uint32_t u = (uint32_t)f2bf(v[0]) | ((uint32_t)f2bf(v[1])<<16);
  *(uint32_t*)(qkv + (size_t)sel*4194304 + (size_t)row*512 + t*2) = u;
}

// ---------- hyp attention-output finish ----------
__global__ __launch_bounds__(256) void o_finish2(const uint16_t* __restrict__ op,
  uint16_t* __restrict__ outb, float* __restrict__ nout)
{
  __shared__ float sb[4];
  const int row = blockIdx.x, t = threadIdx.x;
  const size_t base = (size_t)row*E_ + t*2;
  const uint32_t u = *(const uint32_t*)(op + base);
  float v0 = bf2f(u & 0xFFFFu), v1 = bf2f(u >> 16);
  const float hs = halfsum32(v0*v0 + v1*v1);
  const float ns = sqrtf(hs + 1e-15f);
  const float tt = tanhf(0.5f*artanh_c(ns));
  float scv = tt/ns;
  float sn = tt;
  if(sn > PROJ_M){ scv *= PROJ_M/sn; sn = PROJ_M; }
  v0 *= scv; v1 *= scv;
  const float tot = block_sum(v0*v0 + v1*v1, sb);
  const float n = sqrtf(tot + 1e-15f);
  float nf = n;
  if(n > PROJ_M){ const float s = PROJ_M/n; v0 *= s; v1 *= s; nf = PROJ_M; }
  *(uint32_t*)(outb + base) = (uint32_t)f2bf(v0) | ((uint32_t)f2bf(v1)<<16);
  if(t==0) nout[row] = nf;
}

// ---------- bf16 MFMA GEMM v4: 8-phase-style pipelined schedule ----------
// BM = MF*64 (MF=4 -> 256, MF=2 -> 128), BN=128, BK=64 split into K-32 half-phases.
// 6 LDS half-slots; loads issued 3 halves ahead; counted vmcnt (never 0 in loop);
// setprio around MFMA cluster; one barrier per phase; XCD-swizzled block ids.
// mode: 0 raw->outf; 1 +bias->outb; 2 +bias+res->outf; 3 relu+bias->outb;
//       4 relu+bias+res->outf; 5 raw->outb; 6 QKV-split +bias->outb(QKV contig)
template<int MF>
__global__ __launch_bounds__(512) void gemm8(
    const uint16_t* __restrict__ A, const uint16_t* __restrict__ Bw,
    int M, int N, int K, int mode,
    const float* __restrict__ bias, const float* __restrict__ biasK,
    const float* __restrict__ biasV, const float* __restrict__ res,
    float* __restrict__ outf, uint16_t* __restrict__ outb)
{
  constexpr int SLOT = MF*4096 + 8192;       // A half (BM x 32 bf16) + B half (128 x 32)
  constexpr int LPW  = MF/2 + 1;             // stage loads per wave per half
  __shared__ __align__(16) char lds[6*SLOT];

  const int gx = gridDim.x;                  // N tiles (BN=128)
  int lid = blockIdx.x + gx*blockIdx.y;
  {
    const int nwg = gx*gridDim.y;            // all call sites have nwg % 8 == 0
    const int cpx = nwg >> 3;
    lid = (lid & 7)*cpx + (lid >> 3);        // bijective XCD-contiguous remap
  }
  const int m0 = (lid/gx)*(MF*64);
  const int n0 = (lid%gx)*128;

  const int tid = threadIdx.x;
  const int l = tid & 63, w = tid >> 6;      // 8 waves
  const int wm = w >> 1, wn = w & 1;         // 4x2 wave grid: wave = (MF*16) M x 64 N
  const int lr = l & 15, g = l >> 4;

  // staging constants: each gl_lds16 covers 16 rows x 64 B (one K-32 half-row)
  const int srow = l >> 2;                           // 0..15
  const int schunk8 = (((l & 3) ^ (srow & 3)) << 3); // pre-swizzled source chunk (elems)
  // read-side swizzle: chunk pos = (l>>4) ^ (row&3), row&3 == l&3
  const int posq = (((l >> 4) ^ (l & 3)) << 4);

  f32x4 acc[MF][4];
  #pragma unroll
  for(int i=0;i<MF;i++)
    #pragma unroll
    for(int j=0;j<4;j++) acc[i][j] = (f32x4){0.f,0.f,0.f,0.f};

  const int nk = K >> 6;
  const int nph = nk << 1;

#define STAGE8(ph, slotv) { \
    const int k0_ = ((ph) >> 1)*64 + ((ph) & 1)*32; \
    char* sb_ = (char*)lds + (slotv)*SLOT; \
    _Pragma("unroll") \
    for(int c_=0; c_<MF/2; ++c_){ \
      const int t_ = w*(MF/2) + c_; \
      gl_lds16(A + (size_t)(m0 + t_*16 + srow)*K + k0_ + schunk8, sb_ + t_*1024); \
    } \
    gl_lds16(Bw + (size_t)(n0 + w*16 + srow)*K + k0_ + schunk8, sb_ + MF*4096 + w*1024); \
  }

  STAGE8(0, 0); STAGE8(1, 1); STAGE8(2, 2);
  vwait<2*LPW>();
  __builtin_amdgcn_s_barrier();

  int slot = 0, slot3 = 3;
  for(int p=0; p<nph; ++p){
    const char* sb = (char*)lds + slot*SLOT;
    bf16x8 av[MF], bv[4];
    #pragma unroll
    for(int i=0;i<MF;i++)
      av[i] = *(const bf16x8*)(sb + (wm*(MF*16) + i*16 + lr)*64 + posq);
    #pragma unroll
    for(int j=0;j<4;j++)
      bv[j] = *(const bf16x8*)(sb + MF*4096 + (wn*64 + j*16 + lr)*64 + posq);

    if(p+3 < nph) STAGE8(p+3, slot3);

    __builtin_amdgcn_s_setprio(1);
    #pragma unroll
    for(int i=0;i<MF;i++)
      #pragma unroll
      for(int j=0;j<4;j++)
        acc[i][j] = __builtin_amdgcn_mfma_f32_16x16x32_bf16(av[i], bv[j], acc[i][j], 0,0,0);
    __builtin_amdgcn_s_setprio(0);

    if(p+4 <= nph)      vwait<2*LPW>();   // next slot ready; 2 halves still in flight
    else if(p+3 == nph) vwait<LPW>();
    else if(p+2 == nph) vwait<0>();
    __builtin_amdgcn_s_barrier();
    slot  = (slot  == 5) ? 0 : slot  + 1;
    slot3 = (slot3 == 5) ? 0 : slot3 + 1;
  }
#undef STAGE8

  const int orow = g*4;
  #pragma unroll
  for(int i=0;i<MF;i++){
    #pragma unroll
    for(int j=0;j<4;j++){
      const int gn = n0 + wn*64 + j*16 + lr;
      float bval = 0.f;
      if(mode==1||mode==2||mode==3||mode==4) bval = bias[gn];
      else if(mode==6){
        const float* bp = (gn<512)? bias : ((gn<1024)? biasK : biasV);
        bval = bp[gn&511];
      }
      #pragma unroll
      for(int r=0;r<4;r++){
        const int gm = m0 + wm*(MF*16) + i*16 + orow + r;
        const float vv = acc[i][j][r];
        const size_t off = (size_t)gm*N + gn;
        if(mode==0){ outf[off] = vv; }
        else if(mode==1){ outb[off] = f2bf(vv + bval); }
        else if(mode==2){ outf[off] = vv + bval + res[off]; }
        else if(mode==3){ outb[off] = f2bf(fmaxf(vv + bval, 0.f)); }
        else if(mode==4){ outf[off] = fmaxf(vv + bval, 0.f) + res[off]; }
        else if(mode==5){ outb[off] = f2bf(vv); }
        else {
          outb[(size_t)(gn>>9)*4194304 + (size_t)gm*512 + (gn&511)] = f2bf(vv + bval);
        }
      }
    }
  }
}

// ---------- MFMA flash attention v3: direct-exp softmax, tr-read V, reg-P ----------
template<int HYP>
__global__ __launch_bounds__(256,2) void attn3(
  const uint16_t* __restrict__ Qb, const uint16_t* __restrict__ Kb,
  const uint16_t* __restrict__ Vb, const float* __restrict__ qnG,
  const float* __restrict__ knG, const float* __restrict__ lamG,
  uint16_t* __restrict__ outB)
{
  __shared__ __align__(16) char QsB[16384];     // 2 q-tiles [64][64] bf16 swz
  __shared__ __align__(16) char KsB[2][8192];   // dbuf K tile (epilogue overlay)
  __shared__ __align__(16) char VtB[2][8192];   // dbuf V, tr-subtiled
  __shared__ float kkL[512];
  __shared__ float lamL[512];

  const int tid = threadIdx.x;
  const int l = tid & 63, w = tid >> 6;
  const int lr = l & 15, g = l >> 4;
  const int lr3 = l >> 3, lc = l & 7;
  const int c8s = lc ^ lr3;
  const int swq = (lr & 7) << 4;
  // XCD swizzle: 512 blocks -> each XCD owns 16 consecutive bh groups
  int lid = blockIdx.x + (blockIdx.y << 2);
  lid = (lid & 7)*64 + (lid >> 3);
  const int bh = lid >> 2;
  const int q0 = (lid & 3) * 128;
  const size_t gstride = (size_t)B_*E_;
  const size_t gbase = (size_t)(bh>>3)*E_ + (size_t)(bh&7)*D_;

  // V-staging decode: chunk ci covers LDS elems [w*1024+ci*512+l*8, +8)
  int vs[2], vd[2];
  #pragma unroll
  for(int ci=0;ci<2;ci++){
    vs[ci] = (ci*8 + (l>>3))*4 + ((l>>1)&3);
    vd[ci] = w*16 + (l&1)*8;
  }

  // ---- prologue staging ----
  #pragma unroll
  for(int c=0;c<4;c++){
    const int ci = w*4 + c;
    gl_lds16(Qb + (size_t)(q0 + ci*8 + lr3)*gstride + gbase + c8s*8, QsB + ci*1024);
  }
  #pragma unroll
  for(int c=0;c<2;c++){
    const int ci = w*2 + c;
    gl_lds16(Kb + (size_t)(ci*8 + lr3)*gstride + gbase + c8s*8, KsB[0] + ci*1024);
    gl_lds16(Vb + (size_t)vs[c]*gstride + gbase + vd[c], VtB[0] + w*2048 + c*1024);
  }
  kkL[tid]       = knG[bh*512 + tid];
  kkL[tid + 256] = knG[bh*512 + 256 + tid];
  if(HYP){
    lamL[tid]       = lamG[bh*512 + tid];
    lamL[tid + 256] = lamG[bh*512 + 256 + tid];
  }
  __syncthreads();

  // hoist Q fragments + qq
  const int qrow = w*16 + lr;
  bf16x8 qf[2][2];
  qf[0][0] = *(const bf16x8*)(QsB +        qrow*128 + ((g<<4) ^ swq));
  qf[0][1] = *(const bf16x8*)(QsB +        qrow*128 + (((4+g)<<4) ^ swq));
  qf[1][0] = *(const bf16x8*)(QsB + 8192 + qrow*128 + ((g<<4) ^ swq));
  qf[1][1] = *(const bf16x8*)(QsB + 8192 + qrow*128 + (((4+g)<<4) ^ swq));
  float qq[2];
  qq[0] = qnG[bh*512 + q0 + qrow];
  qq[1] = qnG[bh*512 + q0 + 64 + qrow];

  f32x4 oa[2][4];
  #pragma unroll
  for(int qt=0;qt<2;qt++)
    #pragma unroll
    for(int m=0;m<4;m++) oa[qt][m] = (f32x4){0.f,0.f,0.f,0.f};
  float lrun[2] = {0.f, 0.f};
  float dnr[2]  = {0.f, 0.f};

  const uint32_t vaddr_base = (uint32_t)(uintptr_t)(&VtB[0][0]) + (uint32_t)(l*8);

  for(int kt=0; kt<8; kt++){
    if(kt < 7){
      #pragma unroll
      for(int c=0;c<2;c++){
        const int ci = w*2 + c;
        gl_lds16(Kb + (size_t)((kt+1)*64 + ci*8 + lr3)*gstride + gbase + c8s*8,
                 KsB[(kt+1)&1] + ci*1024);
        gl_lds16(Vb + (size_t)((kt+1)*64 + vs[c])*gstride + gbase + vd[c],
                 VtB[(kt+1)&1] + w*2048 + c*1024);
      }
    }
    const char* Kc = KsB[kt&1];
    const float* kkt = &kkL[kt*64];
    const float* lmt = &lamL[kt*64];

    // ---- scores S^T = K * Q^T, both q-tiles share K fragments ----
    f32x4 st[2][4];
    #pragma unroll
    for(int t=0;t<4;t++){
      const bf16x8 ka0 = *(const bf16x8*)(Kc + (t*16+lr)*128 + ((g<<4) ^ swq));
      const bf16x8 ka1 = *(const bf16x8*)(Kc + (t*16+lr)*128 + (((4+g)<<4) ^ swq));
      f32x4 c0 = (f32x4){0.f,0.f,0.f,0.f};
      f32x4 c1 = (f32x4){0.f,0.f,0.f,0.f};
      c0 = __builtin_amdgcn_mfma_f32_16x16x32_bf16(ka0, qf[0][0], c0, 0,0,0);
      c1 = __builtin_amdgcn_mfma_f32_16x16x32_bf16(ka0, qf[1][0], c1, 0,0,0);
      c0 = __builtin_amdgcn_mfma_f32_16x16x32_bf16(ka1, qf[0][1], c0, 0,0,0);
      c1 = __builtin_amdgcn_mfma_f32_16x16x32_bf16(ka1, qf[1][1], c1, 0,0,0);
      st[0][t] = c0; st[1][t] = c1;
    }

    // ---- transform: p = exp(score) directly (all scores <= 0) ----
    uint32_t pbw[2][8];
    #pragma unroll
    for(int qt=0; qt<2; qt++){
      const float q2 = qq[qt];
      float ls = 0.f, dl = 0.f;
      #pragma unroll
      for(int t=0;t<4;t++){
        const f32x4 kkv = *(const f32x4*)(kkt + t*16 + g*4);
        float p[4];
        #pragma unroll
        for(int r=0;r<4;r++){
          const float qk = st[qt][t][r], kk = kkv[r];
          const float a = q2 + kk;
          if(HYP){
            const float u = fmaxf(fmaf(-2.f, qk, a), 0.f);
            const float v = fmaxf(fmaf(q2, kk, fmaf(-2.f, qk, 1.f)), EPSF);
            const float wz = __builtin_amdgcn_sqrtf(u*v);
            const float den = (u + v) + 2.f*wz;
            float ratio = (v - u) * __builtin_amdgcn_rcpf(den);
            ratio = fmaxf(ratio, 5.9604645e-8f);   // = (1-MAXT)/(1+MAXT) -> p_min 0.125
            p[r] = __builtin_amdgcn_exp2f(0.125f * __builtin_amdgcn_logf(ratio));
          } else {
            const float d2 = fmaxf(fmaf(-2.f, qk, a), 0.f) + 1e-12f;
            p[r] = __builtin_amdgcn_exp2f(-0.18033688f * __builtin_amdgcn_sqrtf(d2));
          }
        }
        ls += (p[0]+p[1])+(p[2]+p[3]);
        if(HYP){
          const f32x4 lv = *(const f32x4*)(lmt + t*16 + g*4);
          dl += p[0]*(lv[0]-1.f) + p[1]*(lv[1]-1.f) + p[2]*(lv[2]-1.f) + p[3]*(lv[3]-1.f);
        }
        pbw[qt][t*2]   = cvtpk(p[0], p[1]);
        pbw[qt][t*2+1] = cvtpk(p[2], p[3]);
      }
      ls += __shfl_xor(ls,16); ls += __shfl_xor(ls,32);
      lrun[qt] += ls;
      if(HYP){
        dl += __shfl_xor(dl,16); dl += __shfl_xor(dl,32);
        dnr[qt] += dl;
      }
    }

    // ---- PV: O^T += V^T * P^T ; V via ds_read_b64_tr_b16, P from registers ----
    const uint32_t va_kt = vaddr_base + (uint32_t)((kt&1)*8192);
    {
      u32x2 r00=trrd<0>(va_kt),    r01=trrd<512>(va_kt);
      u32x2 r10=trrd<2048>(va_kt), r11=trrd<2560>(va_kt);
      u32x2 r20=trrd<4096>(va_kt), r21=trrd<4608>(va_kt);
      u32x2 r30=trrd<6144>(va_kt), r31=trrd<6656>(va_kt);
      asm volatile("s_waitcnt lgkmcnt(0)" ::: "memory");
      __builtin_amdgcn_sched_barrier(0);
      bf16x8 pb0, pb1;
      { union{uint32_t u[4]; bf16x8 v;} c;
        c.u[0]=pbw[0][0]; c.u[1]=pbw[0][1]; c.u[2]=pbw[0][2]; c.u[3]=pbw[0][3]; pb0=c.v; }
      { union{uint32_t u[4]; bf16x8 v;} c;
        c.u[0]=pbw[1][0]; c.u[1]=pbw[1][1]; c.u[2]=pbw[1][2]; c.u[3]=pbw[1][3]; pb1=c.v; }
      __builtin_amdgcn_s_setprio(1);
      bf16x8 va;
      va = vcomb(r00,r01);
      oa[0][0] = __builtin_amdgcn_mfma_f32_16x16x32_bf16(va, pb0, oa[0][0], 0,0,0);
      oa[1][0] = __builtin_amdgcn_mfma_f32_16x16x32_bf16(va, pb1, oa[1][0], 0,0,0);
      va = vcomb(r10,r11);
      oa[0][1] = __builtin_amdgcn_mfma_f32_16x16x32_bf16(va, pb0, oa[0][1], 0,0,0);
      oa[1][1] = __builtin_amdgcn_mfma_f32_16x16x32_bf16(va, pb1, oa[1][1], 0,0,0);
      va = vcomb(r20,r21);
      oa[0][2] = __builtin_amdgcn_mfma_f32_16x16x32_bf16(va, pb0, oa[0][2], 0,0,0);
      oa[1][2] = __builtin_amdgcn_mfma_f32_16x16x32_bf16(va, pb1, oa[1][2], 0,0,0);
      va = vcomb(r30,r31);
      oa[0][3] = __builtin_amdgcn_mfma_f32_16x16x32_bf16(va, pb0, oa[0][3], 0,0,0);
      oa[1][3] = __builtin_amdgcn_mfma_f32_16x16x32_bf16(va, pb1, oa[1][3], 0,0,0);
      __builtin_amdgcn_s_setprio(0);
    }
    {
      u32x2 r00=trrd<1024>(va_kt), r01=trrd<1536>(va_kt);
      u32x2 r10=trrd<3072>(va_kt), r11=trrd<3584>(va_kt);
      u32x2 r20=trrd<5120>(va_kt), r21=trrd<5632>(va_kt);
      u32x2 r30=trrd<7168>(va_kt), r31=trrd<7680>(va_kt);
      asm volatile("s_waitcnt lgkmcnt(0)" ::: "memory");
      __builtin_amdgcn_sched_barrier(0);
      bf16x8 pb0, pb1;
      { union{uint32_t u[4]; bf16x8 v;} c;
        c.u[0]=pbw[0][4]; c.u[1]=pbw[0][5]; c.u[2]=pbw[0][6]; c.u[3]=pbw[0][7]; pb0=c.v; }
      { union{uint32_t u[4]; bf16x8 v;} c;
        c.u[0]=pbw[1][4]; c.u[1]=pbw[1][5]; c.u[2]=pbw[1][6]; c.u[3]=pbw[1][7]; pb1=c.v; }
      __builtin_amdgcn_s_setprio(1);
      bf16x8 va;
      va = vcomb(r00,r01);
      oa[0][0] = __builtin_amdgcn_mfma_f32_16x16x32_bf16(va, pb0, oa[0][0], 0,0,0);
      oa[1][0] = __builtin_amdgcn_mfma_f32_16x16x32_bf16(va, pb1, oa[1][0], 0,0,0);
      va = vcomb(r10,r11);
      oa[0][1] = __builtin_amdgcn_mfma_f32_16x16x32_bf16(va, pb0, oa[0][1], 0,0,0);
      oa[1][1] = __builtin_amdgcn_mfma_f32_16x16x32_bf16(va, pb1, oa[1][1], 0,0,0);
      va = vcomb(r20,r21);
      oa[0][2] = __builtin_amdgcn_mfma_f32_16x16x32_bf16(va, pb0, oa[0][2], 0,0,0);
      oa[1][2] = __builtin_amdgcn_mfma_f32_16x16x32_bf16(va, pb1, oa[1][2], 0,0,0);
      va = vcomb(r30,r31);
      oa[0][3] = __builtin_amdgcn_mfma_f32_16x16x32_bf16(va, pb0, oa[0][3], 0,0,0);
      oa[1][3] = __builtin_amdgcn_mfma_f32_16x16x32_bf16(va, pb1, oa[1][3], 0,0,0);
      __builtin_amdgcn_s_setprio(0);
    }
    __syncthreads();   // one barrier per kt: staging drained, buffers swap
  }

  // ---- epilogue: restage via LDS overlay (on K dbuf), coalesced store ----
  char* OTB = (char*)KsB;
  #pragma unroll
  for(int qt=0; qt<2; qt++){
    float scale;
    {
      const float invl = 1.f/lrun[qt];
      if(HYP){
        const float dn = fmaxf(dnr[qt]*invl, EPSF);
        scale = invl/dn;
      } else scale = invl;
    }
    __syncthreads();
    #pragma unroll
    for(int m=0;m<4;m++){
      f32x4 vv;
      vv[0]=oa[qt][m][0]*scale; vv[1]=oa[qt][m][1]*scale;
      vv[2]=oa[qt][m][2]*scale; vv[3]=oa[qt][m][3]*scale;
      *(f32x4*)(OTB + w*4096 + lr*256 + ((m*64 + g*16) ^ ((lr&7)<<4))) = vv;
    }
    __syncthreads();
    {
      const int row = tid >> 2, cw = tid & 3;
      const int wsrc = row >> 4, ql = row & 15;
      float vals[16];
      #pragma unroll
      for(int ii=0;ii<4;ii++)
        *(f32x4*)&vals[ii*4] = *(const f32x4*)(OTB + wsrc*4096 + ql*256 + ((cw*64 + ii*16) ^ ((ql&7)<<4)));
      const size_t go = (size_t)(q0 + qt*64 + row)*gstride + gbase + cw*16;
      *(uint4*)(outB + go)     = pack8(vals);
      *(uint4*)(outB + go + 8) = pack8(vals+8);
    }
  }
}

// =====================================================================
extern "C" void kernel_launch(void* const* d_in, const int* in_sizes, int n_in,
                              void* d_out, int out_size, void* d_ws, size_t ws_size,
                              hipStream_t stream)
{
  (void)in_sizes; (void)n_in; (void)out_size; (void)ws_size;
  const float* x    = (const float*)d_in[0];
  const float* ln1g = (const float*)d_in[1];
  const float* ln1b = (const float*)d_in[2];
  const float* ln2g = (const float*)d_in[3];
  const float* ln2b = (const float*)d_in[4];
  const float* Wq = (const float*)d_in[5];
  const float* bq = (const float*)d_in[6];
  const float* Wk = (const float*)d_in[7];
  const float* bk = (const float*)d_in[8];
  const float* Wv = (const float*)d_in[9];
  const float* bv = (const float*)d_in[10];
  const float* Wo = (const float*)d_in[11];
  const float* bo = (const float*)d_in[12];
  const float* W1 = (const float*)d_in[13];
  const float* b1 = (const float*)d_in[14];
  const float* W2 = (const float*)d_in[15];
  const float* b2 = (const float*)d_in[16];
  float* out = (float*)d_out;

  char* ws = (char*)d_ws;
  uint16_t* MXb = (uint16_t*)(ws);                          // 24MB bf16 GEMM scratch
  float*    X2  = (float*)   (ws + ((size_t)24<<20));       // 16MB fp32
  uint16_t* HB  = (uint16_t*)(ws + ((size_t)40<<20));       // 8MB
  uint16_t* QB  = (uint16_t*)(ws + ((size_t)48<<20));       // 8MB (Q,K,V contiguous)
  uint16_t* KB  = (uint16_t*)(ws + ((size_t)56<<20));
  uint16_t* VB  = (uint16_t*)(ws + ((size_t)64<<20));
  uint16_t* OB  = (uint16_t*)(ws + ((size_t)72<<20));
  uint16_t* F1B = (uint16_t*)(ws + ((size_t)80<<20));       // 32MB
  uint16_t* WB  = (uint16_t*)(ws + ((size_t)112<<20));      // 12MB (both experts)
  float*    YV  = (float*)   (ws + ((size_t)124<<20));      // expmap'd biases
  float*    NH  = (float*)   (ws + ((size_t)124<<20) + (64<<10));
  float*    NO  = NH + R_;
  float*    N3  = NO + R_;
  float*    N4  = N3 + R_;
  float*    qnG = (float*)   (ws + ((size_t)125<<20));      // [128][512]
  float*    knG = qnG + 65536;
  float*    lamG= knG + 65536;

  // ---- weights + biases (both experts) ----
  cvt_all<<<6144,256,0,stream>>>(Wq,Wk,Wv,Wo,W1,W2, WB);
  expmap_all<<<6,256,0,stream>>>(bq,bk,bv,bo,b1,b2, YV);

  // ================= Expert 0: Euclidean =================
  ln_k<<<R_,256,0,stream>>>(x, ln1g, ln1b, HB);
  gemm8<4><<<dim3(12,32),512,0,stream>>>(HB, WB, R_,1536,512, 6, bq, bk, bv, nullptr, nullptr, QB);
  qk_norms<<<2048,256,0,stream>>>(QB, KB, qnG, knG);
  attn3<0><<<dim3(4,128),256,0,stream>>>(QB, KB, VB, qnG, knG, nullptr, OB);
  gemm8<2><<<dim3(4,64),512,0,stream>>>(OB, WB+786432, R_,512,512, 2, bo, nullptr,nullptr, x, X2, nullptr);
  ln_k<<<R_,256,0,stream>>>(X2, ln2g, ln2b, HB);
  gemm8<4><<<dim3(16,32),512,0,stream>>>(HB, WB+1048576, R_,2048,512, 3, b1, nullptr,nullptr, nullptr, nullptr, F1B);
  gemm8<2><<<dim3(4,64),512,0,stream>>>(F1B, WB+2097152, R_,512,2048, 4, b2, nullptr,nullptr, X2, out, nullptr);

  // ================= Expert 1: Hyperbolic =================
  const float* x1 = x + (size_t)R_*E_;
  uint16_t* WBe = WB + 3145728;
  hyp_lnexp<<<R_,256,0,stream>>>(x1, ln1g+E_, ln1b+E_, HB, NH, 0);
  gemm8<4><<<dim3(12,32),512,0,stream>>>(HB, WBe, R_,1536,512, 5, nullptr,nullptr,nullptr,nullptr, nullptr, MXb);
  man_epi_qkv<<<dim3(R_,3),256,0,stream>>>(MXb, NH, YV, QB, qnG, knG, lamG);
  attn3<1><<<dim3(4,128),256,0,stream>>>(QB, KB, VB, qnG, knG, lamG, OB);
  o_finish2<<<R_,256,0,stream>>>(OB, HB, NO);
  gemm8<2><<<dim3(4,64),512,0,stream>>>(HB, WBe+786432, R_,512,512, 5, nullptr,nullptr,nullptr,nullptr, nullptr, MXb);
  man_epi<2><<<R_,256,0,stream>>>(MXb, NO, YV+1539, nullptr, nullptr, x1, X2, 0);
  hyp_lnexp<<<R_,256,0,stream>>>(X2, ln2g+E_, ln2b+E_, HB, N3, 1);
  gemm8<4><<<dim3(16,32),512,0,stream>>>(HB, WBe+1048576, R_,2048,512, 5, nullptr,nullptr,nullptr,nullptr, nullptr, F1B);
  man_epi<8><<<R_,256,0,stream>>>(F1B, N3, YV+2052, F1B, N4, nullptr, nullptr, 1);
  gemm8<2><<<dim3(4,64),512,0,stream>>>(F1B, WBe+2097152, R_,512,2048, 5, nullptr,nullptr,nullptr,nullptr, nullptr, MXb);
  man_epi<2><<<R_,256,0,stream>>>(MXb, N4, YV+4101, nullptr, nullptr, X2, out + (size_t)R_*E_, 1|8);
}

// Round 8
// 504.306 us; speedup vs baseline: 1.0312x; 1.0312x over previous
//
#include <hip/hip_runtime.h>
#include <cstdint>
#include <cstddef>

#define S_ 512
#define B_ 16
#define H_ 8
#define D_ 64
#define E_ 512
#define FFN_ 2048
#define R_ (S_*B_)          // 8192 rows per expert
#define EPSF 1e-6f
#define PROJ_M 0.99999f     // 1 - 1e-5

typedef __attribute__((ext_vector_type(8))) short bf16x8;
typedef __attribute__((ext_vector_type(4))) float f32x4;
typedef __attribute__((ext_vector_type(2))) unsigned int u32x2;

// ---------- helpers ----------
__device__ __forceinline__ float bf2f(uint32_t u){
  union{uint32_t i; float f;} c; c.i = u<<16; return c.f;
}
__device__ __forceinline__ uint16_t f2bf(float f){
  union{float f; uint32_t i;} c; c.f = f;
  return (uint16_t)((c.i + 0x7FFFu + ((c.i>>16)&1u))>>16);
}
__device__ __forceinline__ void unpack8(uint4 u, float* f){
  f[0]=bf2f(u.x&0xFFFFu); f[1]=bf2f(u.x>>16);
  f[2]=bf2f(u.y&0xFFFFu); f[3]=bf2f(u.y>>16);
  f[4]=bf2f(u.z&0xFFFFu); f[5]=bf2f(u.z>>16);
  f[6]=bf2f(u.w&0xFFFFu); f[7]=bf2f(u.w>>16);
}
__device__ __forceinline__ uint4 pack8(const float* f){
  uint4 u;
  u.x = (uint32_t)f2bf(f[0]) | ((uint32_t)f2bf(f[1])<<16);
  u.y = (uint32_t)f2bf(f[2]) | ((uint32_t)f2bf(f[3])<<16);
  u.z = (uint32_t)f2bf(f[4]) | ((uint32_t)f2bf(f[5])<<16);
  u.w = (uint32_t)f2bf(f[6]) | ((uint32_t)f2bf(f[7])<<16);
  return u;
}
__device__ __forceinline__ float artanh_c(float x){
  return (x >= 0.99999994f) ? 8.4056215f : atanhf(x);
}
__device__ __forceinline__ float wave_sum(float x){
  #pragma unroll
  for(int o=32;o>=1;o>>=1) x += __shfl_xor(x,o);
  return x;
}
__device__ __forceinline__ float halfsum32(float x){
  #pragma unroll
  for(int o=16;o>=1;o>>=1) x += __shfl_xor(x,o);
  return x;
}
__device__ __forceinline__ float block_sum(float x, float* sb){
  x = wave_sum(x);
  const int w = threadIdx.x >> 6;
  __syncthreads();
  if((threadIdx.x & 63)==0) sb[w] = x;
  __syncthreads();
  return sb[0]+sb[1]+sb[2]+sb[3];
}
// async global->LDS, 16B per lane; LDS dest = wave-uniform base + lane*16
__device__ __forceinline__ void gl_lds16(const void* g, void* l){
  __builtin_amdgcn_global_load_lds(
    (const __attribute__((address_space(1))) void*)(uintptr_t)g,
    (__attribute__((address_space(3))) void*)(uint32_t)(uintptr_t)l, 16, 0, 0);
}
__device__ __forceinline__ uint32_t cvtpk(float a, float b){
  uint32_t r;
  asm("v_cvt_pk_bf16_f32 %0, %1, %2" : "=v"(r) : "v"(a), "v"(b));
  return r;
}
template<int OFF>
__device__ __forceinline__ u32x2 trrd(uint32_t addr){
  u32x2 r;
  asm volatile("ds_read_b64_tr_b16 %0, %1 offset:%2" : "=v"(r) : "v"(addr), "n"(OFF));
  return r;
}
__device__ __forceinline__ bf16x8 vcomb(u32x2 a, u32x2 b){
  union{ uint32_t u[4]; bf16x8 v; } c;
  c.u[0]=a[0]; c.u[1]=a[1]; c.u[2]=b[0]; c.u[3]=b[1];
  return c.v;
}

// ---------- all weights fp32 -> bf16 (both experts), one launch ----------
__global__ __launch_bounds__(256) void cvt_all(
  const float* __restrict__ Wq, const float* __restrict__ Wk,
  const float* __restrict__ Wv, const float* __restrict__ Wo,
  const float* __restrict__ W1, const float* __restrict__ W2,
  uint16_t* __restrict__ dst)
{
  int i4 = blockIdx.x*256 + threadIdx.x;   // 4-elem units, total 1572864
  int e = 0;
  if(i4 >= 786432){ e = 1; i4 -= 786432; }
  const int r = i4;
  const float* s;
  if(r < 65536)        s = Wq + (size_t)(r)*4        + (size_t)e*262144;
  else if(r < 131072)  s = Wk + (size_t)(r-65536)*4  + (size_t)e*262144;
  else if(r < 196608)  s = Wv + (size_t)(r-131072)*4 + (size_t)e*262144;
  else if(r < 262144)  s = Wo + (size_t)(r-196608)*4 + (size_t)e*262144;
  else if(r < 524288)  s = W1 + (size_t)(r-262144)*4 + (size_t)e*1048576;
  else                 s = W2 + (size_t)(r-524288)*4 + (size_t)e*1048576;
  const float4 f = *(const float4*)s;
  uint2 o;
  o.x = (uint32_t)f2bf(f.x) | ((uint32_t)f2bf(f.y)<<16);
  o.y = (uint32_t)f2bf(f.z) | ((uint32_t)f2bf(f.w)<<16);
  *(uint2*)(dst + (size_t)e*3145728 + (size_t)r*4) = o;
}

// ---------- expmap0 of all 6 expert-1 biases ----------
__global__ __launch_bounds__(256) void expmap_all(
  const float* __restrict__ bq, const float* __restrict__ bk,
  const float* __restrict__ bv, const float* __restrict__ bo,
  const float* __restrict__ b1, const float* __restrict__ b2,
  float* __restrict__ YV)
{
  __shared__ float sb[4];
  const int id = blockIdx.x, t = threadIdx.x;
  const float* src; float* dst; int C;
  if(id==0){ src=bq+E_;   dst=YV+0;    C=E_; }
  else if(id==1){ src=bk+E_;   dst=YV+513;  C=E_; }
  else if(id==2){ src=bv+E_;   dst=YV+1026; C=E_; }
  else if(id==3){ src=bo+E_;   dst=YV+1539; C=E_; }
  else if(id==4){ src=b1+FFN_; dst=YV+2052; C=FFN_; }
  else          { src=b2+E_;   dst=YV+4101; C=E_; }
  const int npc = C >> 8;
  float v[8]; float s2 = 0.f;
  for(int i=0;i<npc;i++){ v[i] = src[t+256*i]; s2 += v[i]*v[i]; }
  s2 = block_sum(s2, sb);
  const float n = sqrtf(s2 + 1e-15f);
  const float th = tanhf(n);
  const float sc = th/n;
  for(int i=0;i<npc;i++) dst[t+256*i] = v[i]*sc;
  if(t==0) dst[C] = th*th;
}

// ---------- fused LN for both experts: rows [0,8192) euclid LN, [8192,16384) hyp expmap0(LN) ----------
// x is a contiguous [16384][512] fp32 buffer (expert-0 rows then expert-1 rows).
// g,b are [2][512]. nout indexed by row-8192 (hyp rows only).
__global__ __launch_bounds__(256) void lnfuse(const float* __restrict__ x,
  const float* __restrict__ g, const float* __restrict__ b,
  uint16_t* __restrict__ out, float* __restrict__ nout, int do_projx)
{
  __shared__ float sb[4];
  const int row = blockIdx.x, t = threadIdx.x;
  const size_t base = (size_t)row*E_;
  const int hyp = (row >= R_);
  const float* gg = g + (hyp? E_ : 0);
  const float* bb = b + (hyp? E_ : 0);
  float v0 = x[base+t], v1 = x[base+t+256];
  const float mu  = block_sum(v0+v1, sb) * (1.f/E_);
  const float d0 = v0-mu, d1 = v1-mu;
  const float var = block_sum(d0*d0+d1*d1, sb) * (1.f/E_);
  const float rs = 1.f/sqrtf(var + 1e-5f);
  float t0 = d0*rs*gg[t] + bb[t];
  float t1 = d1*rs*gg[t+256] + bb[t+256];
  if(hyp){
    const float n2s = block_sum(t0*t0+t1*t1, sb);
    const float n2 = sqrtf(n2s + 1e-15f);
    const float nh = tanhf(n2);
    const float scl = nh/n2;
    t0 *= scl; t1 *= scl;
    float nrm = nh;
    if(do_projx && nrm > PROJ_M){ const float s = PROJ_M/nrm; t0*=s; t1*=s; nrm = PROJ_M; }
    if(t==0) nout[row - R_] = nrm;
  }
  out[base+t] = f2bf(t0); out[base+t+256] = f2bf(t1);
}

// ---------- per-head squared norms of euclid Q,K (layout [b*8+h][s]) ----------
__global__ __launch_bounds__(256) void qk_norms(
  const uint16_t* __restrict__ Qb, const uint16_t* __restrict__ Kb,
  float* __restrict__ qn, float* __restrict__ kn)
{
  const int w = threadIdx.x >> 6, l = threadIdx.x & 63;
  const int row = blockIdx.x*4 + w;
  const int s = row >> 4, b = row & 15;
  const size_t base = (size_t)row*E_ + l*8;
  {
    uint4 u = *(const uint4*)(Qb + base);
    float f[8]; unpack8(u, f);
    float ss = 0.f;
    #pragma unroll
    for(int i=0;i<8;i++) ss += f[i]*f[i];
    ss += __shfl_xor(ss,1); ss += __shfl_xor(ss,2); ss += __shfl_xor(ss,4);
    if((l&7)==0) qn[((b<<3) + (l>>3))*512 + s] = ss;
  }
  {
    uint4 u = *(const uint4*)(Kb + base);
    float f[8]; unpack8(u, f);
    float ss = 0.f;
    #pragma unroll
    for(int i=0;i<8;i++) ss += f[i]*f[i];
    ss += __shfl_xor(ss,1); ss += __shfl_xor(ss,2); ss += __shfl_xor(ss,4);
    if((l&7)==0) kn[((b<<3) + (l>>3))*512 + s] = ss;
  }
}

// ---------- man_linear epilogue (generic): flags 1 relu; 8 projx on midpoint ----------
template<int NPC>
__global__ __launch_bounds__(256) void man_epi(
  const uint16_t* __restrict__ mxb, const float* __restrict__ nxbuf,
  const float* __restrict__ y, uint16_t* __restrict__ outb,
  float* __restrict__ nout,
  const float* __restrict__ midres, float* __restrict__ midout, int flags)
{
  constexpr int C = NPC*256;
  __shared__ float sb[4];
  const int row = blockIdx.x, t = threadIdx.x;
  const size_t base = (size_t)row*C + (size_t)t*NPC;
  float v[NPC], yv[NPC];
  if(NPC==2){
    const uint32_t u = *(const uint32_t*)(mxb + base);
    v[0] = bf2f(u & 0xFFFFu); v[1] = bf2f(u >> 16);
  } else {
    const uint4 u = *(const uint4*)(mxb + base);
    unpack8(u, v);
  }
  float s2 = 0.f;
  #pragma unroll
  for(int i=0;i<NPC;i++){ yv[i] = y[t*NPC + i]; s2 += v[i]*v[i]; }
  s2 = block_sum(s2, sb);
  const float nmx = sqrtf(s2 + 1e-15f);
  const float nx  = nxbuf[row];
  const float sc  = tanhf(nmx/nx * artanh_c(nx));
  const bool ok   = (nmx > 1e-7f);
  const float fmul = ok ? (sc/nmx) : 0.f;
  const float x2   = ok ? sc*sc : 0.f;
  float xy = 0.f;
  #pragma unroll
  for(int i=0;i<NPC;i++){ v[i] *= fmul; xy += v[i]*yv[i]; }
  xy = block_sum(xy, sb);
  const float y2 = y[C];
  const float aa = 1.f + 2.f*xy + y2;
  const float bb = 1.f - x2;
  const float iden = 1.f/fmaxf(1.f + 2.f*xy + x2*y2, EPSF);
  const float num2 = aa*aa*x2 + 2.f*aa*bb*xy + bb*bb*y2;
  const float nz = sqrtf(num2*iden*iden + 1e-15f);
  const float ps = (nz > PROJ_M) ? (PROJ_M/nz) : 1.f;
  float nfin = (nz > PROJ_M) ? PROJ_M : nz;
  #pragma unroll
  for(int i=0;i<NPC;i++) v[i] = (aa*v[i] + bb*yv[i]) * iden * ps;
  if(flags & 1){
    float rs = 0.f;
    #pragma unroll
    for(int i=0;i<NPC;i++){ v[i] = fmaxf(v[i], 0.f); rs += v[i]*v[i]; }
    rs = block_sum(rs, sb);
    nfin = sqrtf(rs + 1e-15f);
  }
  if(midres){
    float bv2[NPC];
    float pb = 0.f, pab = 0.f;
    #pragma unroll
    for(int i=0;i<NPC;i++){ bv2[i] = midres[base + i]; pb += bv2[i]*bv2[i]; pab += v[i]*bv2[i]; }
    const float sa  = nfin*nfin;
    const float sbb = block_sum(pb, sb);
    const float sab = block_sum(pab, sb);
    const float l1 = 2.f/fmaxf(1.f - sa,  EPSF);
    const float l2 = 2.f/fmaxf(1.f - sbb, EPSF);
    const float idn = 1.f/fmaxf(l1 + l2 - 2.f, EPSF);
    const float nt2 = (l1*l1*sa + 2.f*l1*l2*sab + l2*l2*sbb)*idn*idn;
    const float nt = sqrtf(nt2 + 1e-15f);
    const float sfin = tanhf(0.5f*artanh_c(nt));
    float scm = sfin/nt;
    if((flags & 8) && sfin > PROJ_M) scm *= PROJ_M/sfin;
    #pragma unroll
    for(int i=0;i<NPC;i++) midout[base + i] = (v[i]*l1 + bv2[i]*l2)*idn*scm;
  } else {
    if(NPC==2){
      uint32_t u = (uint32_t)f2bf(v[0]) | ((uint32_t)f2bf(v[1])<<16);
      *(uint32_t*)(outb + base) = u;
    } else {
      *(uint4*)(outb + base) = pack8(v);
    }
    if(nout && t==0) nout[row] = nfin;
  }
}

// ---------- fused hyp q/k/v man_linear epilogue (IN-PLACE on [sel][row][512] layout) ----------
__global__ __launch_bounds__(256) void man_epi_qkv(
  const uint16_t* __restrict__ mxb, const float* __restrict__ nxbuf,
  const float* __restrict__ YV, uint16_t* __restrict__ qkv,
  float* __restrict__ qnG, float* __restrict__ knG, float* __restrict__ lamG)
{
  __shared__ float sb[4];
  const int sel = blockIdx.y;
  const int row = blockIdx.x, t = threadIdx.x;
  const float* y = YV + sel*513;
  float v[2], yv[2];
  {
    const uint32_t u = *(const uint32_t*)(mxb + (size_t)sel*4194304 + (size_t)row*512 + t*2);
    v[0] = bf2f(u & 0xFFFFu); v[1] = bf2f(u >> 16);
  }
  float s2 = 0.f;
  #pragma unroll
  for(int i=0;i<2;i++){ yv[i] = y[t*2 + i]; s2 += v[i]*v[i]; }
  s2 = block_sum(s2, sb);
  const float nmx = sqrtf(s2 + 1e-15f);
  const float nx  = nxbuf[row];
  const float sc  = tanhf(nmx/nx * artanh_c(nx));
  const bool ok   = (nmx > 1e-7f);
  const float fmul = ok ? (sc/nmx) : 0.f;
  const float x2   = ok ? sc*sc : 0.f;
  float xy = 0.f;
  #pragma unroll
  for(int i=0;i<2;i++){ v[i] *= fmul; xy += v[i]*yv[i]; }
  xy = block_sum(xy, sb);
  const float y2 = y[512];
  const float aa = 1.f + 2.f*xy + y2;
  const float bb = 1.f - x2;
  const float iden = 1.f/fmaxf(1.f + 2.f*xy + x2*y2, EPSF);
  const float num2 = aa*aa*x2 + 2.f*aa*bb*xy + bb*bb*y2;
  const float nz = sqrtf(num2*iden*iden + 1e-15f);
  const float ps = (nz > PROJ_M) ? (PROJ_M/nz) : 1.f;
  #pragma unroll
  for(int i=0;i<2;i++) v[i] = (aa*v[i] + bb*yv[i]) * iden * ps;
  // per-head projx (+ lambda)
  float hs = halfsum32(v[0]*v[0] + v[1]*v[1]);
  float nh = sqrtf(hs + 1e-15f);
  float phs = 1.f;
  if(nh > PROJ_M){ phs = PROJ_M/nh; nh = PROJ_M; }
  v[0] *= phs; v[1] *= phs;
  const float nh2 = nh*nh;
  const float lam = 2.f/fmaxf(1.f - nh2, EPSF);
  if(sel==2){ v[0] *= lam; v[1] *= lam; }
  if((t & 31) == 0){
    const int s = row >> 4, b = row & 15;
    const int idx = ((b<<3) + (t>>5))*512 + s;
    if(sel==0) qnG[idx] = nh2;
    else if(sel==1) knG[idx] = nh2;
    else lamG[idx] = lam;
  }
  uint32_t u = (uint32_t)f2bf(v[0]) | ((uint32_t)f2bf(v[1])<<16);
  *(uint32_t*)(qkv + (size_t)sel*4194304 + (size_t)row*512 + t*2) = u;
}

// ---------- hyp attention-output finish (in-place) ----------
__global__ __launch_bounds__(256) void o_finish2(const uint16_t* __restrict__ op,
  uint16_t* __restrict__ outb, float* __restrict__ nout)
{
  __shared__ float sb[4];
  const int row = blockIdx.x, t = threadIdx.x;
  const size_t base = (size_t)row*E_ + t*2;
  const uint32_t u = *(const uint32_t*)(op + base);
  float v0 = bf2f(u & 0xFFFFu), v1 = bf2f(u >> 16);
  const float hs = halfsum32(v0*v0 + v1*v1);
  const float ns = sqrtf(hs + 1e-15f);
  const float tt = tanhf(0.5f*artanh_c(ns));
  float scv = tt/ns;
  float sn = tt;
  if(sn > PROJ_M){ scv *= PROJ_M/sn; sn = PROJ_M; }
  v0 *= scv; v1 *= scv;
  const float tot = block_sum(v0*v0 + v1*v1, sb);
  const float n = sqrtf(tot + 1e-15f);
  float nf = n;
  if(n > PROJ_M){ const float s = PROJ_M/n; v0 *= s; v1 *= s; nf = PROJ_M; }
  *(uint32_t*)(outb + base) = (uint32_t)f2bf(v0) | ((uint32_t)f2bf(v1)<<16);
  if(t==0) nout[row] = nf;
}

// ---------- bf16 MFMA GEMM (fusable over 2 experts): C = A[M,K] @ W^T ----------
// 128x128 tile, BK=64, dbuf, 256 threads, XCD-swizzled, expert-split by m-range.
// modes: 2 +bias+res->outf(fp32); 3 relu+bias->outb; 4 relu+bias+res->outf;
//        5 raw->outb; 6 QKV-split +bias->outb; 7 QKV-split raw->outb
__global__ __launch_bounds__(256) void gemmF(
    const uint16_t* __restrict__ A,
    const uint16_t* __restrict__ Bw0, const uint16_t* __restrict__ Bw1,
    int msplit, int N, int K, int mode0, int mode1,
    const float* __restrict__ bQ, const float* __restrict__ bK,
    const float* __restrict__ bV, const float* __restrict__ res0,
    float* __restrict__ outf0,
    uint16_t* __restrict__ outb0, uint16_t* __restrict__ outb1)
{
  __shared__ __align__(16) char AsB[2][16384];
  __shared__ __align__(16) char BsB[2][16384];
  const int gx = gridDim.x;
  int lid = blockIdx.x + gx*blockIdx.y;
  {
    const int nwg = gx*gridDim.y;           // all call sites have nwg % 8 == 0
    const int cpx = nwg >> 3;
    lid = (lid & 7)*cpx + (lid >> 3);       // bijective XCD-contiguous remap
  }
  const int m0 = (lid/gx)*128;
  const int n0 = (lid%gx)*128;
  const int e  = (m0 >= msplit);
  const uint16_t* Bw = e ? Bw1 : Bw0;
  uint16_t* ob = e ? outb1 : outb0;
  const int mode = e ? mode1 : mode0;
  const int mloc0 = m0 - (e ? msplit : 0);

  const int tid = threadIdx.x;
  const int l = tid & 63, w = tid >> 6;
  const int wm = w >> 1, wn = w & 1;
  const int lr = l & 15, g = l >> 4;
  const int lr3 = l >> 3, lc = l & 7;
  const int c8s = lc ^ lr3;
  const int swq = (lr & 7) << 4;

  const uint16_t* aSrc = A  + (size_t)(m0 + lr3)*K + c8s*8;
  const uint16_t* bSrc = Bw + (size_t)(n0 + lr3)*K + c8s*8;

  f32x4 acc[4][4];
  #pragma unroll
  for(int i=0;i<4;i++)
    #pragma unroll
    for(int j=0;j<4;j++) acc[i][j] = (f32x4){0.f,0.f,0.f,0.f};

  const int nk = K >> 6;
  #pragma unroll
  for(int c=0;c<4;c++){
    const int ci = w*4 + c;
    gl_lds16(aSrc + (size_t)(ci*8)*K, AsB[0] + ci*1024);
    gl_lds16(bSrc + (size_t)(ci*8)*K, BsB[0] + ci*1024);
  }
  for(int ks=0; ks<nk; ks++){
    __syncthreads();
    if(ks+1 < nk){
      const int k0 = (ks+1) << 6;
      #pragma unroll
      for(int c=0;c<4;c++){
        const int ci = w*4 + c;
        gl_lds16(aSrc + (size_t)(ci*8)*K + k0, AsB[(ks+1)&1] + ci*1024);
        gl_lds16(bSrc + (size_t)(ci*8)*K + k0, BsB[(ks+1)&1] + ci*1024);
      }
    }
    const char* Ac = AsB[ks&1];
    const char* Bc = BsB[ks&1];
    #pragma unroll
    for(int h=0;h<2;h++){
      bf16x8 av[4], bv[4];
      #pragma unroll
      for(int i=0;i<4;i++){
        av[i] = *(const bf16x8*)(Ac + (wm*64 + i*16 + lr)*128 + ((((h*4+g)<<4)) ^ swq));
        bv[i] = *(const bf16x8*)(Bc + (wn*64 + i*16 + lr)*128 + ((((h*4+g)<<4)) ^ swq));
      }
      #pragma unroll
      for(int i=0;i<4;i++)
        #pragma unroll
        for(int j=0;j<4;j++)
          acc[i][j] = __builtin_amdgcn_mfma_f32_16x16x32_bf16(av[i], bv[j], acc[i][j], 0,0,0);
    }
  }
  const int orow = g*4;
  #pragma unroll
  for(int i=0;i<4;i++){
    #pragma unroll
    for(int j=0;j<4;j++){
      const int gn = n0 + wn*64 + j*16 + lr;
      float bval = 0.f;
      if(mode==2||mode==3||mode==4) bval = bQ[gn];
      else if(mode==6){
        const float* bp = (gn<512)? bQ : ((gn<1024)? bK : bV);
        bval = bp[gn&511];
      }
      #pragma unroll
      for(int r=0;r<4;r++){
        const int gml = mloc0 + wm*64 + i*16 + orow + r;
        const float vv = acc[i][j][r];
        const size_t off = (size_t)gml*N + gn;
        if(mode==2){ outf0[off] = vv + bval + res0[off]; }
        else if(mode==3){ ob[off] = f2bf(fmaxf(vv + bval, 0.f)); }
        else if(mode==4){ outf0[off] = fmaxf(vv + bval, 0.f) + res0[off]; }
        else if(mode==5){ ob[off] = f2bf(vv); }
        else { // 6 / 7: QKV scatter [sel][row][512]
          ob[(size_t)(gn>>9)*4194304 + (size_t)gml*512 + (gn&511)] = f2bf(vv + bval);
        }
      }
    }
  }
}

// ---------- fused MFMA flash attention (both experts, runtime hyp flag) ----------
__global__ __launch_bounds__(256,2) void attnF(
  const uint16_t* __restrict__ QKV0, const uint16_t* __restrict__ QKV1,
  const float* __restrict__ qn0, const float* __restrict__ kn0,
  const float* __restrict__ qn1, const float* __restrict__ kn1,
  const float* __restrict__ lam1, uint16_t* __restrict__ OB)
{
  __shared__ __align__(16) char QsB[16384];     // 2 q-tiles [64][64] bf16 swz
  __shared__ __align__(16) char KsB[2][8192];   // dbuf K tile (epilogue overlay)
  __shared__ __align__(16) char VtB[2][8192];   // dbuf V, tr-subtiled
  __shared__ float kkL[512];
  __shared__ float lamL[512];

  const int tid = threadIdx.x;
  const int l = tid & 63, w = tid >> 6;
  const int lr = l & 15, g = l >> 4;
  const int lr3 = l >> 3, lc = l & 7;
  const int c8s = lc ^ lr3;
  const int swq = (lr & 7) << 4;
  // XCD swizzle over 1024 blocks; work id partitions experts
  int lid = blockIdx.x;
  lid = (lid & 7)*128 + (lid >> 3);
  const int hyp = lid >> 9;
  const int sub = lid & 511;
  const int bh = sub >> 2;
  const int q0 = (sub & 3) * 128;
  const uint16_t* Qb = hyp ? QKV1 : QKV0;
  const uint16_t* Kb = Qb + 4194304;
  const uint16_t* Vb = Qb + 8388608;
  const float* qnG = hyp ? qn1 : qn0;
  const float* knG = hyp ? kn1 : kn0;
  uint16_t* outB = OB + (size_t)hyp*4194304;
  const size_t gstride = (size_t)B_*E_;
  const size_t gbase = (size_t)(bh>>3)*E_ + (size_t)(bh&7)*D_;

  // V-staging decode: chunk ci covers LDS elems [w*1024+ci*512+l*8, +8)
  int vs[2], vd[2];
  #pragma unroll
  for(int ci=0;ci<2;ci++){
    vs[ci] = (ci*8 + (l>>3))*4 + ((l>>1)&3);
    vd[ci] = w*16 + (l&1)*8;
  }

  // ---- prologue staging ----
  #pragma unroll
  for(int c=0;c<4;c++){
    const int ci = w*4 + c;
    gl_lds16(Qb + (size_t)(q0 + ci*8 + lr3)*gstride + gbase + c8s*8, QsB + ci*1024);
  }
  #pragma unroll
  for(int c=0;c<2;c++){
    const int ci = w*2 + c;
    gl_lds16(Kb + (size_t)(ci*8 + lr3)*gstride + gbase + c8s*8, KsB[0] + ci*1024);
    gl_lds16(Vb + (size_t)vs[c]*gstride + gbase + vd[c], VtB[0] + w*2048 + c*1024);
  }
  kkL[tid]       = knG[bh*512 + tid];
  kkL[tid + 256] = knG[bh*512 + 256 + tid];
  if(hyp){
    lamL[tid]       = lam1[bh*512 + tid];
    lamL[tid + 256] = lam1[bh*512 + 256 + tid];
  }
  __syncthreads();

  // hoist Q fragments + qq
  const int qrow = w*16 + lr;
  bf16x8 qf[2][2];
  qf[0][0] = *(const bf16x8*)(QsB +        qrow*128 + ((g<<4) ^ swq));
  qf[0][1] = *(const bf16x8*)(QsB +        qrow*128 + (((4+g)<<4) ^ swq));
  qf[1][0] = *(const bf16x8*)(QsB + 8192 + qrow*128 + ((g<<4) ^ swq));
  qf[1][1] = *(const bf16x8*)(QsB + 8192 + qrow*128 + (((4+g)<<4) ^ swq));
  float qq[2];
  qq[0] = qnG[bh*512 + q0 + qrow];
  qq[1] = qnG[bh*512 + q0 + 64 + qrow];

  f32x4 oa[2][4];
  #pragma unroll
  for(int qt=0;qt<2;qt++)
    #pragma unroll
    for(int m=0;m<4;m++) oa[qt][m] = (f32x4){0.f,0.f,0.f,0.f};
  float lrun[2] = {0.f, 0.f};
  float dnr[2]  = {0.f, 0.f};

  const uint32_t vaddr_base = (uint32_t)(uintptr_t)(&VtB[0][0]) + (uint32_t)(l*8);

  for(int kt=0; kt<8; kt++){
    if(kt < 7){
      #pragma unroll
      for(int c=0;c<2;c++){
        const int ci = w*2 + c;
        gl_lds16(Kb + (size_t)((kt+1)*64 + ci*8 + lr3)*gstride + gbase + c8s*8,
                 KsB[(kt+1)&1] + ci*1024);
        gl_lds16(Vb + (size_t)((kt+1)*64 + vs[c])*gstride + gbase + vd[c],
                 VtB[(kt+1)&1] + w*2048 + c*1024);
      }
    }
    const char* Kc = KsB[kt&1];
    const float* kkt = &kkL[kt*64];
    const float* lmt = &lamL[kt*64];

    // ---- scores S^T = K * Q^T, both q-tiles share K fragments ----
    f32x4 st[2][4];
    #pragma unroll
    for(int t=0;t<4;t++){
      const bf16x8 ka0 = *(const bf16x8*)(Kc + (t*16+lr)*128 + ((g<<4) ^ swq));
      const bf16x8 ka1 = *(const bf16x8*)(Kc + (t*16+lr)*128 + (((4+g)<<4) ^ swq));
      f32x4 c0 = (f32x4){0.f,0.f,0.f,0.f};
      f32x4 c1 = (f32x4){0.f,0.f,0.f,0.f};
      c0 = __builtin_amdgcn_mfma_f32_16x16x32_bf16(ka0, qf[0][0], c0, 0,0,0);
      c1 = __builtin_amdgcn_mfma_f32_16x16x32_bf16(ka0, qf[1][0], c1, 0,0,0);
      c0 = __builtin_amdgcn_mfma_f32_16x16x32_bf16(ka1, qf[0][1], c0, 0,0,0);
      c1 = __builtin_amdgcn_mfma_f32_16x16x32_bf16(ka1, qf[1][1], c1, 0,0,0);
      st[0][t] = c0; st[1][t] = c1;
    }

    // ---- transform: p = exp(score) directly (all scores <= 0) ----
    uint32_t pbw[2][8];
    #pragma unroll
    for(int qt=0; qt<2; qt++){
      const float q2 = qq[qt];
      float ls = 0.f, dl = 0.f;
      #pragma unroll
      for(int t=0;t<4;t++){
        const f32x4 kkv = *(const f32x4*)(kkt + t*16 + g*4);
        float p[4];
        #pragma unroll
        for(int r=0;r<4;r++){
          const float qk = st[qt][t][r], kk = kkv[r];
          const float a = q2 + kk;
          if(hyp){
            const float u = fmaxf(fmaf(-2.f, qk, a), 0.f);
            const float v = fmaxf(fmaf(q2, kk, fmaf(-2.f, qk, 1.f)), EPSF);
            const float wz = __builtin_amdgcn_sqrtf(u*v);
            const float den = (u + v) + 2.f*wz;
            float ratio = (v - u) * __builtin_amdgcn_rcpf(den);
            ratio = fmaxf(ratio, 5.9604645e-8f);   // -> p_min = 0.125
            p[r] = __builtin_amdgcn_exp2f(0.125f * __builtin_amdgcn_logf(ratio));
          } else {
            const float d2 = fmaxf(fmaf(-2.f, qk, a), 0.f) + 1e-12f;
            p[r] = __builtin_amdgcn_exp2f(-0.18033688f * __builtin_amdgcn_sqrtf(d2));
          }
        }
        ls += (p[0]+p[1])+(p[2]+p[3]);
        if(hyp){
          const f32x4 lv = *(const f32x4*)(lmt + t*16 + g*4);
          dl += p[0]*(lv[0]-1.f) + p[1]*(lv[1]-1.f) + p[2]*(lv[2]-1.f) + p[3]*(lv[3]-1.f);
        }
        pbw[qt][t*2]   = cvtpk(p[0], p[1]);
        pbw[qt][t*2+1] = cvtpk(p[2], p[3]);
      }
      ls += __shfl_xor(ls,16); ls += __shfl_xor(ls,32);
      lrun[qt] += ls;
      if(hyp){
        dl += __shfl_xor(dl,16); dl += __shfl_xor(dl,32);
        dnr[qt] += dl;
      }
    }

    // ---- PV: O^T += V^T * P^T ; V via ds_read_b64_tr_b16, P from registers ----
    const uint32_t va_kt = vaddr_base + (uint32_t)((kt&1)*8192);
    {
      u32x2 r00=trrd<0>(va_kt),    r01=trrd<512>(va_kt);
      u32x2 r10=trrd<2048>(va_kt), r11=trrd<2560>(va_kt);
      u32x2 r20=trrd<4096>(va_kt), r21=trrd<4608>(va_kt);
      u32x2 r30=trrd<6144>(va_kt), r31=trrd<6656>(va_kt);
      asm volatile("s_waitcnt lgkmcnt(0)" ::: "memory");
      __builtin_amdgcn_sched_barrier(0);
      bf16x8 pb0, pb1;
      { union{uint32_t u[4]; bf16x8 v;} c;
        c.u[0]=pbw[0][0]; c.u[1]=pbw[0][1]; c.u[2]=pbw[0][2]; c.u[3]=pbw[0][3]; pb0=c.v; }
      { union{uint32_t u[4]; bf16x8 v;} c;
        c.u[0]=pbw[1][0]; c.u[1]=pbw[1][1]; c.u[2]=pbw[1][2]; c.u[3]=pbw[1][3]; pb1=c.v; }
      __builtin_amdgcn_s_setprio(1);
      bf16x8 va;
      va = vcomb(r00,r01);
      oa[0][0] = __builtin_amdgcn_mfma_f32_16x16x32_bf16(va, pb0, oa[0][0], 0,0,0);
      oa[1][0] = __builtin_amdgcn_mfma_f32_16x16x32_bf16(va, pb1, oa[1][0], 0,0,0);
      va = vcomb(r10,r11);
      oa[0][1] = __builtin_amdgcn_mfma_f32_16x16x32_bf16(va, pb0, oa[0][1], 0,0,0);
      oa[1][1] = __builtin_amdgcn_mfma_f32_16x16x32_bf16(va, pb1, oa[1][1], 0,0,0);
      va = vcomb(r20,r21);
      oa[0][2] = __builtin_amdgcn_mfma_f32_16x16x32_bf16(va, pb0, oa[0][2], 0,0,0);
      oa[1][2] = __builtin_amdgcn_mfma_f32_16x16x32_bf16(va, pb1, oa[1][2], 0,0,0);
      va = vcomb(r30,r31);
      oa[0][3] = __builtin_amdgcn_mfma_f32_16x16x32_bf16(va, pb0, oa[0][3], 0,0,0);
      oa[1][3] = __builtin_amdgcn_mfma_f32_16x16x32_bf16(va, pb1, oa[1][3], 0,0,0);
      __builtin_amdgcn_s_setprio(0);
    }
    {
      u32x2 r00=trrd<1024>(va_kt), r01=trrd<1536>(va_kt);
      u32x2 r10=trrd<3072>(va_kt), r11=trrd<3584>(va_kt);
      u32x2 r20=trrd<5120>(va_kt), r21=trrd<5632>(va_kt);
      u32x2 r30=trrd<7168>(va_kt), r31=trrd<7680>(va_kt);
      asm volatile("s_waitcnt lgkmcnt(0)" ::: "memory");
      __builtin_amdgcn_sched_barrier(0);
      bf16x8 pb0, pb1;
      { union{uint32_t u[4]; bf16x8 v;} c;
        c.u[0]=pbw[0][4]; c.u[1]=pbw[0][5]; c.u[2]=pbw[0][6]; c.u[3]=pbw[0][7]; pb0=c.v; }
      { union{uint32_t u[4]; bf16x8 v;} c;
        c.u[0]=pbw[1][4]; c.u[1]=pbw[1][5]; c.u[2]=pbw[1][6]; c.u[3]=pbw[1][7]; pb1=c.v; }
      __builtin_amdgcn_s_setprio(1);
      bf16x8 va;
      va = vcomb(r00,r01);
      oa[0][0] = __builtin_amdgcn_mfma_f32_16x16x32_bf16(va, pb0, oa[0][0], 0,0,0);
      oa[1][0] = __builtin_amdgcn_mfma_f32_16x16x32_bf16(va, pb1, oa[1][0], 0,0,0);
      va = vcomb(r10,r11);
      oa[0][1] = __builtin_amdgcn_mfma_f32_16x16x32_bf16(va, pb0, oa[0][1], 0,0,0);
      oa[1][1] = __builtin_amdgcn_mfma_f32_16x16x32_bf16(va, pb1, oa[1][1], 0,0,0);
      va = vcomb(r20,r21);
      oa[0][2] = __builtin_amdgcn_mfma_f32_16x16x32_bf16(va, pb0, oa[0][2], 0,0,0);
      oa[1][2] = __builtin_amdgcn_mfma_f32_16x16x32_bf16(va, pb1, oa[1][2], 0,0,0);
      va = vcomb(r30,r31);
      oa[0][3] = __builtin_amdgcn_mfma_f32_16x16x32_bf16(va, pb0, oa[0][3], 0,0,0);
      oa[1][3] = __builtin_amdgcn_mfma_f32_16x16x32_bf16(va, pb1, oa[1][3], 0,0,0);
      __builtin_amdgcn_s_setprio(0);
    }
    __syncthreads();   // one barrier per kt: staging drained, buffers swap
  }

  // ---- epilogue: restage via LDS overlay (on K dbuf), coalesced store ----
  char* OTB = (char*)KsB;
  #pragma unroll
  for(int qt=0; qt<2; qt++){
    float scale;
    {
      const float invl = 1.f/lrun[qt];
      if(hyp){
        const float dn = fmaxf(dnr[qt]*invl, EPSF);
        scale = invl/dn;
      } else scale = invl;
    }
    __syncthreads();
    #pragma unroll
    for(int m=0;m<4;m++){
      f32x4 vv;
      vv[0]=oa[qt][m][0]*scale; vv[1]=oa[qt][m][1]*scale;
      vv[2]=oa[qt][m][2]*scale; vv[3]=oa[qt][m][3]*scale;
      *(f32x4*)(OTB + w*4096 + lr*256 + ((m*64 + g*16) ^ ((lr&7)<<4))) = vv;
    }
    __syncthreads();
    {
      const int row = tid >> 2, cw = tid & 3;
      const int wsrc = row >> 4, ql = row & 15;
      float vals[16];
      #pragma unroll
      for(int ii=0;ii<4;ii++)
        *(f32x4*)&vals[ii*4] = *(const f32x4*)(OTB + wsrc*4096 + ql*256 + ((cw*64 + ii*16) ^ ((ql&7)<<4)));
      const size_t go = (size_t)(q0 + qt*64 + row)*gstride + gbase + cw*16;
      *(uint4*)(outB + go)     = pack8(vals);
      *(uint4*)(outB + go + 8) = pack8(vals+8);
    }
  }
}

// =====================================================================
extern "C" void kernel_launch(void* const* d_in, const int* in_sizes, int n_in,
                              void* d_out, int out_size, void* d_ws, size_t ws_size,
                              hipStream_t stream)
{
  (void)in_sizes; (void)n_in; (void)out_size; (void)ws_size;
  const float* x    = (const float*)d_in[0];
  const float* ln1g = (const float*)d_in[1];
  const float* ln1b = (const float*)d_in[2];
  const float* ln2g = (const float*)d_in[3];
  const float* ln2b = (const float*)d_in[4];
  const float* Wq = (const float*)d_in[5];
  const float* bq = (const float*)d_in[6];
  const float* Wk = (const float*)d_in[7];
  const float* bk = (const float*)d_in[8];
  const float* Wv = (const float*)d_in[9];
  const float* bv = (const float*)d_in[10];
  const float* Wo = (const float*)d_in[11];
  const float* bo = (const float*)d_in[12];
  const float* W1 = (const float*)d_in[13];
  const float* b1 = (const float*)d_in[14];
  const float* W2 = (const float*)d_in[15];
  const float* b2 = (const float*)d_in[16];
  float* out = (float*)d_out;
  const float* x1 = x + (size_t)R_*E_;

  char* ws = (char*)d_ws;
  uint16_t* HB   = (uint16_t*)(ws);                         // 16MB [16384][512] bf16
  uint16_t* QKV0 = (uint16_t*)(ws + ((size_t)16<<20));      // 24MB [3][8192][512]
  uint16_t* QKV1 = (uint16_t*)(ws + ((size_t)40<<20));      // 24MB
  uint16_t* F1B  = (uint16_t*)(ws + ((size_t)16<<20));      // 32MB alias (post-attn)
  uint16_t* OB   = (uint16_t*)(ws + ((size_t)64<<20));      // 16MB [16384][512]
  float*    X2   = (float*)   (ws + ((size_t)80<<20));      // 32MB fp32 [16384][512] (e0,e1)
  float*    X2e1 = X2 + (size_t)R_*E_;
  uint16_t* WB   = (uint16_t*)(ws + ((size_t)112<<20));     // 12MB (both experts)
  char*     aux  = ws + ((size_t)124<<20);
  float*    YV   = (float*)(aux);                           // expmap'd biases (~17KB)
  float*    NH   = (float*)(aux + (32<<10));
  float*    NO   = NH + R_;
  float*    N3   = NO + R_;
  float*    N4   = N3 + R_;
  float*    qn0  = (float*)(aux + (256<<10));
  float*    kn0  = qn0 + 65536;
  float*    qn1  = kn0 + 65536;
  float*    kn1  = qn1 + 65536;
  float*    lam1 = kn1 + 65536;

  uint16_t* WBe = WB + 3145728;

  // ---- weights + biases (both experts) ----
  cvt_all<<<6144,256,0,stream>>>(Wq,Wk,Wv,Wo,W1,W2, WB);
  expmap_all<<<6,256,0,stream>>>(bq,bk,bv,bo,b1,b2, YV);

  // ---- LN1 both experts (x is contiguous [2][8192][512]) ----
  lnfuse<<<2*R_,256,0,stream>>>(x, ln1g, ln1b, HB, NH, 0);

  // ---- fused QKV GEMM: e0 -> QKV0 (+bias), e1 -> QKV1 raw ----
  gemmF<<<dim3(12,128),256,0,stream>>>(HB, WB, WBe, R_, 1536, 512, 6, 7,
                                       bq, bk, bv, nullptr, nullptr, QKV0, QKV1);
  qk_norms<<<2048,256,0,stream>>>(QKV0, QKV0+4194304, qn0, kn0);
  man_epi_qkv<<<dim3(R_,3),256,0,stream>>>(QKV1, NH, YV, QKV1, qn1, kn1, lam1);

  // ---- fused attention (1024 blocks: 512 euclid + 512 hyp) ----
  attnF<<<1024,256,0,stream>>>(QKV0, QKV1, qn0, kn0, qn1, kn1, lam1, OB);
  o_finish2<<<R_,256,0,stream>>>(OB + (size_t)R_*E_, OB + (size_t)R_*E_, NO);

  // ---- fused projection GEMM: e0 -> X2 (+bias+res x), e1 raw -> HB ----
  gemmF<<<dim3(4,128),256,0,stream>>>(OB, WB+786432, WBe+786432, R_, 512, 512, 2, 5,
                                      bo, nullptr, nullptr, x, X2, nullptr, HB);
  man_epi<2><<<R_,256,0,stream>>>(HB, NO, YV+1539, nullptr, nullptr, x1, X2e1, 0);

  // ---- LN2 both experts (X2 contiguous) ----
  lnfuse<<<2*R_,256,0,stream>>>(X2, ln2g, ln2b, HB, N3, 1);

  // ---- FFN expert 0 ----
  gemmF<<<dim3(16,64),256,0,stream>>>(HB, WB+1048576, nullptr, 1<<30, 2048, 512, 3, 0,
                                      b1, nullptr, nullptr, nullptr, nullptr, F1B, nullptr);
  gemmF<<<dim3(4,64),256,0,stream>>>(F1B, WB+2097152, nullptr, 1<<30, 512, 2048, 4, 0,
                                     b2, nullptr, nullptr, X2, out, nullptr, nullptr);

  // ---- FFN expert 1 ----
  gemmF<<<dim3(16,64),256,0,stream>>>(HB + (size_t)R_*E_, WBe+1048576, nullptr, 1<<30,
                                      2048, 512, 5, 0,
                                      nullptr, nullptr, nullptr, nullptr, nullptr, F1B, nullptr);
  man_epi<8><<<R_,256,0,stream>>>(F1B, N3, YV+2052, F1B, N4, nullptr, nullptr, 1);
  gemmF<<<dim3(4,64),256,0,stream>>>(F1B, WBe+2097152, nullptr, 1<<30, 512, 2048, 5, 0,
                                     nullptr, nullptr, nullptr, nullptr, nullptr, HB, nullptr);
  man_epi<2><<<R_,256,0,stream>>>(HB, N4, YV+4101, nullptr, nullptr,
                                  X2e1, out + (size_t)R_*E_, 1|8);
}

// Round 9
// 393.866 us; speedup vs baseline: 1.3204x; 1.2804x over previous
//
#include <hip/hip_runtime.h>
#include <cstdint>
#include <cstddef>

#define S_ 512
#define B_ 16
#define H_ 8
#define D_ 64
#define E_ 512
#define FFN_ 2048
#define R_ (S_*B_)          // 8192 rows per expert
#define EPSF 1e-6f
#define PROJ_M 0.99999f     // 1 - 1e-5

typedef __attribute__((ext_vector_type(8))) short bf16x8;
typedef __attribute__((ext_vector_type(4))) float f32x4;
typedef __attribute__((ext_vector_type(2))) unsigned int u32x2;

// ---------- helpers ----------
__device__ __forceinline__ float bf2f(uint32_t u){
  union{uint32_t i; float f;} c; c.i = u<<16; return c.f;
}
__device__ __forceinline__ uint16_t f2bf(float f){
  union{float f; uint32_t i;} c; c.f = f;
  return (uint16_t)((c.i + 0x7FFFu + ((c.i>>16)&1u))>>16);
}
__device__ __forceinline__ void unpack8(uint4 u, float* f){
  f[0]=bf2f(u.x&0xFFFFu); f[1]=bf2f(u.x>>16);
  f[2]=bf2f(u.y&0xFFFFu); f[3]=bf2f(u.y>>16);
  f[4]=bf2f(u.z&0xFFFFu); f[5]=bf2f(u.z>>16);
  f[6]=bf2f(u.w&0xFFFFu); f[7]=bf2f(u.w>>16);
}
__device__ __forceinline__ uint4 pack8(const float* f){
  uint4 u;
  u.x = (uint32_t)f2bf(f[0]) | ((uint32_t)f2bf(f[1])<<16);
  u.y = (uint32_t)f2bf(f[2]) | ((uint32_t)f2bf(f[3])<<16);
  u.z = (uint32_t)f2bf(f[4]) | ((uint32_t)f2bf(f[5])<<16);
  u.w = (uint32_t)f2bf(f[6]) | ((uint32_t)f2bf(f[7])<<16);
  return u;
}
__device__ __forceinline__ float artanh_c(float x){
  return (x >= 0.99999994f) ? 8.4056215f : atanhf(x);
}
__device__ __forceinline__ float wave_sum(float x){
  #pragma unroll
  for(int o=32;o>=1;o>>=1) x += __shfl_xor(x,o);
  return x;
}
__device__ __forceinline__ float g8sum(float x){
  x += __shfl_xor(x,1); x += __shfl_xor(x,2); x += __shfl_xor(x,4);
  return x;
}
__device__ __forceinline__ float block_sum(float x, float* sb){
  x = wave_sum(x);
  const int w = threadIdx.x >> 6;
  __syncthreads();
  if((threadIdx.x & 63)==0) sb[w] = x;
  __syncthreads();
  return sb[0]+sb[1]+sb[2]+sb[3];
}
// async global->LDS, 16B per lane; LDS dest = wave-uniform base + lane*16
__device__ __forceinline__ void gl_lds16(const void* g, void* l){
  __builtin_amdgcn_global_load_lds(
    (const __attribute__((address_space(1))) void*)(uintptr_t)g,
    (__attribute__((address_space(3))) void*)(uint32_t)(uintptr_t)l, 16, 0, 0);
}
__device__ __forceinline__ uint32_t cvtpk(float a, float b){
  uint32_t r;
  asm("v_cvt_pk_bf16_f32 %0, %1, %2" : "=v"(r) : "v"(a), "v"(b));
  return r;
}
template<int OFF>
__device__ __forceinline__ u32x2 trrd(uint32_t addr){
  u32x2 r;
  asm volatile("ds_read_b64_tr_b16 %0, %1 offset:%2" : "=v"(r) : "v"(addr), "n"(OFF));
  return r;
}
__device__ __forceinline__ bf16x8 vcomb(u32x2 a, u32x2 b){
  union{ uint32_t u[4]; bf16x8 v; } c;
  c.u[0]=a[0]; c.u[1]=a[1]; c.u[2]=b[0]; c.u[3]=b[1];
  return c.v;
}

// ---------- all weights fp32 -> bf16 (both experts), one launch ----------
__global__ __launch_bounds__(256) void cvt_all(
  const float* __restrict__ Wq, const float* __restrict__ Wk,
  const float* __restrict__ Wv, const float* __restrict__ Wo,
  const float* __restrict__ W1, const float* __restrict__ W2,
  uint16_t* __restrict__ dst)
{
  int i4 = blockIdx.x*256 + threadIdx.x;   // 4-elem units, total 1572864
  int e = 0;
  if(i4 >= 786432){ e = 1; i4 -= 786432; }
  const int r = i4;
  const float* s;
  if(r < 65536)        s = Wq + (size_t)(r)*4        + (size_t)e*262144;
  else if(r < 131072)  s = Wk + (size_t)(r-65536)*4  + (size_t)e*262144;
  else if(r < 196608)  s = Wv + (size_t)(r-131072)*4 + (size_t)e*262144;
  else if(r < 262144)  s = Wo + (size_t)(r-196608)*4 + (size_t)e*262144;
  else if(r < 524288)  s = W1 + (size_t)(r-262144)*4 + (size_t)e*1048576;
  else                 s = W2 + (size_t)(r-524288)*4 + (size_t)e*1048576;
  const float4 f = *(const float4*)s;
  uint2 o;
  o.x = (uint32_t)f2bf(f.x) | ((uint32_t)f2bf(f.y)<<16);
  o.y = (uint32_t)f2bf(f.z) | ((uint32_t)f2bf(f.w)<<16);
  *(uint2*)(dst + (size_t)e*3145728 + (size_t)r*4) = o;
}

// ---------- expmap0 of all 6 expert-1 biases (16B-aligned 528-float strides) ----------
__global__ __launch_bounds__(256) void expmap_all(
  const float* __restrict__ bq, const float* __restrict__ bk,
  const float* __restrict__ bv, const float* __restrict__ bo,
  const float* __restrict__ b1, const float* __restrict__ b2,
  float* __restrict__ YV)
{
  __shared__ float sb[4];
  const int id = blockIdx.x, t = threadIdx.x;
  const float* src; float* dst; int C;
  if(id==0){ src=bq+E_;   dst=YV+0;    C=E_; }
  else if(id==1){ src=bk+E_;   dst=YV+528;  C=E_; }
  else if(id==2){ src=bv+E_;   dst=YV+1056; C=E_; }
  else if(id==3){ src=bo+E_;   dst=YV+1584; C=E_; }
  else if(id==4){ src=b1+FFN_; dst=YV+2112; C=FFN_; }
  else          { src=b2+E_;   dst=YV+4176; C=E_; }
  const int npc = C >> 8;
  float v[8]; float s2 = 0.f;
  for(int i=0;i<npc;i++){ v[i] = src[t+256*i]; s2 += v[i]*v[i]; }
  s2 = block_sum(s2, sb);
  const float n = sqrtf(s2 + 1e-15f);
  const float th = tanhf(n);
  const float sc = th/n;
  for(int i=0;i<npc;i++) dst[t+256*i] = v[i]*sc;
  if(t==0) dst[C] = th*th;
}

// ---------- fused LN both experts, WAVE-PER-ROW (no barriers) ----------
// rows [0,8192) euclid LN; [8192,16384) hyp expmap0(LN). 4 rows/block.
__global__ __launch_bounds__(256) void lnfuseW(const float* __restrict__ x,
  const float* __restrict__ g, const float* __restrict__ b,
  uint16_t* __restrict__ out, float* __restrict__ nout, int do_projx)
{
  const int row = blockIdx.x*4 + (threadIdx.x>>6);
  const int l = threadIdx.x & 63;
  const size_t base = (size_t)row*E_ + l*8;
  const int hyp = (row >= R_);
  const float* gg = g + (hyp? E_ : 0);
  const float* bb = b + (hyp? E_ : 0);
  float v[8];
  *(float4*)(v)   = *(const float4*)(x + base);
  *(float4*)(v+4) = *(const float4*)(x + base + 4);
  float s = 0.f;
  #pragma unroll
  for(int i=0;i<8;i++) s += v[i];
  const float mu = wave_sum(s) * (1.f/E_);
  float q = 0.f;
  #pragma unroll
  for(int i=0;i<8;i++){ v[i] -= mu; q += v[i]*v[i]; }
  const float var = wave_sum(q) * (1.f/E_);
  const float rs = 1.f/sqrtf(var + 1e-5f);
  float gv[8], bvv[8];
  *(float4*)(gv)    = *(const float4*)(gg + l*8);
  *(float4*)(gv+4)  = *(const float4*)(gg + l*8 + 4);
  *(float4*)(bvv)   = *(const float4*)(bb + l*8);
  *(float4*)(bvv+4) = *(const float4*)(bb + l*8 + 4);
  float t[8];
  #pragma unroll
  for(int i=0;i<8;i++) t[i] = v[i]*rs*gv[i] + bvv[i];
  if(hyp){
    float n = 0.f;
    #pragma unroll
    for(int i=0;i<8;i++) n += t[i]*t[i];
    n = wave_sum(n);
    const float n2 = sqrtf(n + 1e-15f);
    const float nh = tanhf(n2);
    float scl = nh/n2;
    float nrm = nh;
    if(do_projx && nrm > PROJ_M){ scl *= PROJ_M/nrm; nrm = PROJ_M; }
    #pragma unroll
    for(int i=0;i<8;i++) t[i] *= scl;
    if(l==0) nout[row - R_] = nrm;
  }
  *(uint4*)(out + base) = pack8(t);
}

// ---------- per-head squared norms of euclid Q,K (layout [b*8+h][s]) ----------
__global__ __launch_bounds__(256) void qk_norms(
  const uint16_t* __restrict__ Qb, const uint16_t* __restrict__ Kb,
  float* __restrict__ qn, float* __restrict__ kn)
{
  const int w = threadIdx.x >> 6, l = threadIdx.x & 63;
  const int row = blockIdx.x*4 + w;
  const int s = row >> 4, b = row & 15;
  const size_t base = (size_t)row*E_ + l*8;
  {
    uint4 u = *(const uint4*)(Qb + base);
    float f[8]; unpack8(u, f);
    float ss = 0.f;
    #pragma unroll
    for(int i=0;i<8;i++) ss += f[i]*f[i];
    ss = g8sum(ss);
    if((l&7)==0) qn[((b<<3) + (l>>3))*512 + s] = ss;
  }
  {
    uint4 u = *(const uint4*)(Kb + base);
    float f[8]; unpack8(u, f);
    float ss = 0.f;
    #pragma unroll
    for(int i=0;i<8;i++) ss += f[i]*f[i];
    ss = g8sum(ss);
    if((l&7)==0) kn[((b<<3) + (l>>3))*512 + s] = ss;
  }
}

// ---------- man_linear epilogue, WAVE-PER-ROW. EPL = C/64. flags: 1 relu; 8 projx-mid ----------
template<int EPL>
__global__ __launch_bounds__(256) void man_epiW(
  const uint16_t* __restrict__ mxb, const float* __restrict__ nxbuf,
  const float* __restrict__ y, uint16_t* __restrict__ outb,
  float* __restrict__ nout,
  const float* __restrict__ midres, float* __restrict__ midout, int flags)
{
  constexpr int C = EPL*64;
  const int row = blockIdx.x*4 + (threadIdx.x>>6);
  const int l = threadIdx.x & 63;
  const size_t base = (size_t)row*C + l*EPL;
  float v[EPL], yv[EPL];
  #pragma unroll
  for(int i=0;i<EPL/8;i++){
    uint4 u = *(const uint4*)(mxb + base + i*8);
    unpack8(u, v + i*8);
  }
  #pragma unroll
  for(int i=0;i<EPL/4;i++)
    *(float4*)(yv + i*4) = *(const float4*)(y + l*EPL + i*4);
  float s2 = 0.f;
  #pragma unroll
  for(int i=0;i<EPL;i++) s2 += v[i]*v[i];
  s2 = wave_sum(s2);
  const float nmx = sqrtf(s2 + 1e-15f);
  const float nx  = nxbuf[row];
  const float sc  = tanhf(nmx/nx * artanh_c(nx));
  const bool ok   = (nmx > 1e-7f);
  const float fmul = ok ? (sc/nmx) : 0.f;
  const float x2   = ok ? sc*sc : 0.f;
  float xy = 0.f;
  #pragma unroll
  for(int i=0;i<EPL;i++){ v[i] *= fmul; xy += v[i]*yv[i]; }
  xy = wave_sum(xy);
  const float y2 = y[C];
  const float aa = 1.f + 2.f*xy + y2;
  const float bb = 1.f - x2;
  const float iden = 1.f/fmaxf(1.f + 2.f*xy + x2*y2, EPSF);
  const float num2 = aa*aa*x2 + 2.f*aa*bb*xy + bb*bb*y2;
  const float nz = sqrtf(num2*iden*iden + 1e-15f);
  const float ps = (nz > PROJ_M) ? (PROJ_M/nz) : 1.f;
  float nfin = (nz > PROJ_M) ? PROJ_M : nz;
  #pragma unroll
  for(int i=0;i<EPL;i++) v[i] = (aa*v[i] + bb*yv[i]) * iden * ps;
  if(flags & 1){
    float rsu = 0.f;
    #pragma unroll
    for(int i=0;i<EPL;i++){ v[i] = fmaxf(v[i], 0.f); rsu += v[i]*v[i]; }
    rsu = wave_sum(rsu);
    nfin = sqrtf(rsu + 1e-15f);
  }
  if(midres){
    float bv2[EPL];
    #pragma unroll
    for(int i=0;i<EPL/4;i++)
      *(float4*)(bv2 + i*4) = *(const float4*)(midres + base + i*4);
    float pb = 0.f, pab = 0.f;
    #pragma unroll
    for(int i=0;i<EPL;i++){ pb += bv2[i]*bv2[i]; pab += v[i]*bv2[i]; }
    const float sa  = nfin*nfin;
    const float sbb = wave_sum(pb);
    const float sab = wave_sum(pab);
    const float l1 = 2.f/fmaxf(1.f - sa,  EPSF);
    const float l2 = 2.f/fmaxf(1.f - sbb, EPSF);
    const float idn = 1.f/fmaxf(l1 + l2 - 2.f, EPSF);
    const float nt2 = (l1*l1*sa + 2.f*l1*l2*sab + l2*l2*sbb)*idn*idn;
    const float nt = sqrtf(nt2 + 1e-15f);
    const float sfin = tanhf(0.5f*artanh_c(nt));
    float scm = sfin/nt;
    if((flags & 8) && sfin > PROJ_M) scm *= PROJ_M/sfin;
    #pragma unroll
    for(int i=0;i<EPL;i++) midout[base + i] = (v[i]*l1 + bv2[i]*l2)*idn*scm;
  } else {
    #pragma unroll
    for(int i=0;i<EPL/8;i++)
      *(uint4*)(outb + base + i*8) = pack8(v + i*8);
    if(nout && l==0) nout[row] = nfin;
  }
}

// ---------- fused hyp q/k/v man_linear epilogue, WAVE-PER-ROW (in-place) ----------
__global__ __launch_bounds__(256) void man_epi_qkvW(
  const uint16_t* __restrict__ mxb, const float* __restrict__ nxbuf,
  const float* __restrict__ YV, uint16_t* __restrict__ qkv,
  float* __restrict__ qnG, float* __restrict__ knG, float* __restrict__ lamG)
{
  const int sel = blockIdx.y;
  const int row = blockIdx.x*4 + (threadIdx.x>>6);
  const int l = threadIdx.x & 63;
  const float* y = YV + sel*528;
  const size_t base = (size_t)sel*4194304 + (size_t)row*512 + l*8;
  float v[8], yv[8];
  {
    uint4 u = *(const uint4*)(mxb + base);
    unpack8(u, v);
  }
  *(float4*)(yv)   = *(const float4*)(y + l*8);
  *(float4*)(yv+4) = *(const float4*)(y + l*8 + 4);
  float s2 = 0.f;
  #pragma unroll
  for(int i=0;i<8;i++) s2 += v[i]*v[i];
  s2 = wave_sum(s2);
  const float nmx = sqrtf(s2 + 1e-15f);
  const float nx  = nxbuf[row];
  const float sc  = tanhf(nmx/nx * artanh_c(nx));
  const bool ok   = (nmx > 1e-7f);
  const float fmul = ok ? (sc/nmx) : 0.f;
  const float x2   = ok ? sc*sc : 0.f;
  float xy = 0.f;
  #pragma unroll
  for(int i=0;i<8;i++){ v[i] *= fmul; xy += v[i]*yv[i]; }
  xy = wave_sum(xy);
  const float y2 = y[512];
  const float aa = 1.f + 2.f*xy + y2;
  const float bb = 1.f - x2;
  const float iden = 1.f/fmaxf(1.f + 2.f*xy + x2*y2, EPSF);
  const float num2 = aa*aa*x2 + 2.f*aa*bb*xy + bb*bb*y2;
  const float nz = sqrtf(num2*iden*iden + 1e-15f);
  const float ps = (nz > PROJ_M) ? (PROJ_M/nz) : 1.f;
  #pragma unroll
  for(int i=0;i<8;i++) v[i] = (aa*v[i] + bb*yv[i]) * iden * ps;
  // per-head projx (+ lambda): head = l>>3 (8 lanes x 8 elems = 64)
  float hs = 0.f;
  #pragma unroll
  for(int i=0;i<8;i++) hs += v[i]*v[i];
  hs = g8sum(hs);
  float nh = sqrtf(hs + 1e-15f);
  float phs = 1.f;
  if(nh > PROJ_M){ phs = PROJ_M/nh; nh = PROJ_M; }
  #pragma unroll
  for(int i=0;i<8;i++) v[i] *= phs;
  const float nh2 = nh*nh;
  const float lam = 2.f/fmaxf(1.f - nh2, EPSF);
  if(sel==2){
    #pragma unroll
    for(int i=0;i<8;i++) v[i] *= lam;
  }
  if((l & 7) == 0){
    const int s = row >> 4, b2 = row & 15;
    const int idx = ((b2<<3) + (l>>3))*512 + s;
    if(sel==0) qnG[idx] = nh2;
    else if(sel==1) knG[idx] = nh2;
    else lamG[idx] = lam;
  }
  *(uint4*)(qkv + base) = pack8(v);
}

// ---------- hyp attention-output finish, WAVE-PER-ROW (in-place) ----------
__global__ __launch_bounds__(256) void o_finishW(const uint16_t* __restrict__ op,
  uint16_t* __restrict__ outb, float* __restrict__ nout)
{
  const int row = blockIdx.x*4 + (threadIdx.x>>6);
  const int l = threadIdx.x & 63;
  const size_t base = (size_t)row*E_ + l*8;
  float v[8];
  {
    uint4 u = *(const uint4*)(op + base);
    unpack8(u, v);
  }
  float hs = 0.f;
  #pragma unroll
  for(int i=0;i<8;i++) hs += v[i]*v[i];
  hs = g8sum(hs);
  const float ns = sqrtf(hs + 1e-15f);
  const float tt = tanhf(0.5f*artanh_c(ns));
  float scv = tt/ns;
  float sn = tt;
  if(sn > PROJ_M){ scv *= PROJ_M/sn; sn = PROJ_M; }
  float tot = 0.f;
  #pragma unroll
  for(int i=0;i<8;i++){ v[i] *= scv; tot += v[i]*v[i]; }
  tot = wave_sum(tot);
  const float n = sqrtf(tot + 1e-15f);
  float nf = n;
  if(n > PROJ_M){
    const float s = PROJ_M/n;
    #pragma unroll
    for(int i=0;i<8;i++) v[i] *= s;
    nf = PROJ_M;
  }
  *(uint4*)(outb + base) = pack8(v);
  if(l==0) nout[row] = nf;
}

// ---------- bf16 MFMA GEMM (fusable over 2 experts by m-range) ----------
// 128x128 tile, BK=64, dbuf, 256 threads, XCD-swizzled.
// modes: 2 +bias+res->outf(fp32); 3 relu+bias->outb; 4 relu+bias+res->outf;
//        5 raw->outb; 6 QKV-split +bias->outb; 7 QKV-split raw->outb
__global__ __launch_bounds__(256) void gemmF(
    const uint16_t* __restrict__ A,
    const uint16_t* __restrict__ Bw0, const uint16_t* __restrict__ Bw1,
    int msplit, int N, int K, int mode0, int mode1,
    const float* __restrict__ bQ, const float* __restrict__ bK,
    const float* __restrict__ bV, const float* __restrict__ res0,
    float* __restrict__ outf0,
    uint16_t* __restrict__ outb0, uint16_t* __restrict__ outb1)
{
  __shared__ __align__(16) char AsB[2][16384];
  __shared__ __align__(16) char BsB[2][16384];
  const int gx = gridDim.x;
  int lid = blockIdx.x + gx*blockIdx.y;
  {
    const int nwg = gx*gridDim.y;           // all call sites have nwg % 8 == 0
    const int cpx = nwg >> 3;
    lid = (lid & 7)*cpx + (lid >> 3);       // bijective XCD-contiguous remap
  }
  const int m0 = (lid/gx)*128;
  const int n0 = (lid%gx)*128;
  const int e  = (m0 >= msplit);
  const uint16_t* Bw = e ? Bw1 : Bw0;
  uint16_t* ob = e ? outb1 : outb0;
  const int mode = e ? mode1 : mode0;
  const int mloc0 = m0 - (e ? msplit : 0);

  const int tid = threadIdx.x;
  const int l = tid & 63, w = tid >> 6;
  const int wm = w >> 1, wn = w & 1;
  const int lr = l & 15, g = l >> 4;
  const int lr3 = l >> 3, lc = l & 7;
  const int c8s = lc ^ lr3;
  const int swq = (lr & 7) << 4;

  const uint16_t* aSrc = A  + (size_t)(m0 + lr3)*K + c8s*8;
  const uint16_t* bSrc = Bw + (size_t)(n0 + lr3)*K + c8s*8;

  f32x4 acc[4][4];
  #pragma unroll
  for(int i=0;i<4;i++)
    #pragma unroll
    for(int j=0;j<4;j++) acc[i][j] = (f32x4){0.f,0.f,0.f,0.f};

  const int nk = K >> 6;
  #pragma unroll
  for(int c=0;c<4;c++){
    const int ci = w*4 + c;
    gl_lds16(aSrc + (size_t)(ci*8)*K, AsB[0] + ci*1024);
    gl_lds16(bSrc + (size_t)(ci*8)*K, BsB[0] + ci*1024);
  }
  for(int ks=0; ks<nk; ks++){
    __syncthreads();
    if(ks+1 < nk){
      const int k0 = (ks+1) << 6;
      #pragma unroll
      for(int c=0;c<4;c++){
        const int ci = w*4 + c;
        gl_lds16(aSrc + (size_t)(ci*8)*K + k0, AsB[(ks+1)&1] + ci*1024);
        gl_lds16(bSrc + (size_t)(ci*8)*K + k0, BsB[(ks+1)&1] + ci*1024);
      }
    }
    const char* Ac = AsB[ks&1];
    const char* Bc = BsB[ks&1];
    #pragma unroll
    for(int h=0;h<2;h++){
      bf16x8 av[4], bv[4];
      #pragma unroll
      for(int i=0;i<4;i++){
        av[i] = *(const bf16x8*)(Ac + (wm*64 + i*16 + lr)*128 + ((((h*4+g)<<4)) ^ swq));
        bv[i] = *(const bf16x8*)(Bc + (wn*64 + i*16 + lr)*128 + ((((h*4+g)<<4)) ^ swq));
      }
      #pragma unroll
      for(int i=0;i<4;i++)
        #pragma unroll
        for(int j=0;j<4;j++)
          acc[i][j] = __builtin_amdgcn_mfma_f32_16x16x32_bf16(av[i], bv[j], acc[i][j], 0,0,0);
    }
  }
  const int orow = g*4;
  #pragma unroll
  for(int i=0;i<4;i++){
    #pragma unroll
    for(int j=0;j<4;j++){
      const int gn = n0 + wn*64 + j*16 + lr;
      float bval = 0.f;
      if(mode==2||mode==3||mode==4) bval = bQ[gn];
      else if(mode==6){
        const float* bp = (gn<512)? bQ : ((gn<1024)? bK : bV);
        bval = bp[gn&511];
      }
      #pragma unroll
      for(int r=0;r<4;r++){
        const int gml = mloc0 + wm*64 + i*16 + orow + r;
        const float vv = acc[i][j][r];
        const size_t off = (size_t)gml*N + gn;
        if(mode==2){ outf0[off] = vv + bval + res0[off]; }
        else if(mode==3){ ob[off] = f2bf(fmaxf(vv + bval, 0.f)); }
        else if(mode==4){ outf0[off] = fmaxf(vv + bval, 0.f) + res0[off]; }
        else if(mode==5){ ob[off] = f2bf(vv); }
        else { // 6 / 7: QKV scatter [sel][row][512]
          ob[(size_t)(gn>>9)*4194304 + (size_t)gml*512 + (gn&511)] = f2bf(vv + bval);
        }
      }
    }
  }
}

// ---------- fused MFMA flash attention v4: 2048 blocks, one 64-row q-tile each ----------
__global__ __launch_bounds__(256,3) void attnF2(
  const uint16_t* __restrict__ QKV0, const uint16_t* __restrict__ QKV1,
  const float* __restrict__ qn0, const float* __restrict__ kn0,
  const float* __restrict__ qn1, const float* __restrict__ kn1,
  const float* __restrict__ lam1, uint16_t* __restrict__ OB)
{
  __shared__ __align__(16) char QsB[8192];      // [64][64] bf16 swz
  __shared__ __align__(16) char KsB[2][8192];   // dbuf K tile (epilogue overlay)
  __shared__ __align__(16) char VtB[2][8192];   // dbuf V, tr-subtiled
  __shared__ float kkL[512];
  __shared__ float lamL[512];

  const int tid = threadIdx.x;
  const int l = tid & 63, w = tid >> 6;
  const int lr = l & 15, g = l >> 4;
  const int lr3 = l >> 3, lc = l & 7;
  const int c8s = lc ^ lr3;
  const int swq = (lr & 7) << 4;
  // XCD swizzle over 2048 blocks; lid partitions: [expert][bh][qtile]
  int lid = blockIdx.x;
  lid = (lid & 7)*256 + (lid >> 3);
  const int hyp = lid >> 10;
  const int sub = lid & 1023;
  const int bh = sub >> 3;
  const int q0 = (sub & 7) * 64;
  const uint16_t* Qb = hyp ? QKV1 : QKV0;
  const uint16_t* Kb = Qb + 4194304;
  const uint16_t* Vb = Qb + 8388608;
  const float* qnG = hyp ? qn1 : qn0;
  const float* knG = hyp ? kn1 : kn0;
  uint16_t* outB = OB + (size_t)hyp*4194304;
  const size_t gstride = (size_t)B_*E_;
  const size_t gbase = (size_t)(bh>>3)*E_ + (size_t)(bh&7)*D_;

  // V-staging decode: chunk ci covers LDS elems [w*1024+ci*512+l*8, +8)
  int vs[2], vd[2];
  #pragma unroll
  for(int ci=0;ci<2;ci++){
    vs[ci] = (ci*8 + (l>>3))*4 + ((l>>1)&3);
    vd[ci] = w*16 + (l&1)*8;
  }

  // ---- prologue staging ----
  #pragma unroll
  for(int c=0;c<2;c++){
    const int ci = w*2 + c;
    gl_lds16(Qb + (size_t)(q0 + ci*8 + lr3)*gstride + gbase + c8s*8, QsB + ci*1024);
    gl_lds16(Kb + (size_t)(ci*8 + lr3)*gstride + gbase + c8s*8, KsB[0] + ci*1024);
    gl_lds16(Vb + (size_t)vs[c]*gstride + gbase + vd[c], VtB[0] + w*2048 + c*1024);
  }
  kkL[tid]       = knG[bh*512 + tid];
  kkL[tid + 256] = knG[bh*512 + 256 + tid];
  if(hyp){
    lamL[tid]       = lam1[bh*512 + tid];
    lamL[tid + 256] = lam1[bh*512 + 256 + tid];
  }
  __syncthreads();

  // hoist Q fragments + qq
  const int qrow = w*16 + lr;
  bf16x8 qf0, qf1;
  qf0 = *(const bf16x8*)(QsB + qrow*128 + ((g<<4) ^ swq));
  qf1 = *(const bf16x8*)(QsB + qrow*128 + (((4+g)<<4) ^ swq));
  const float qq = qnG[bh*512 + q0 + qrow];

  f32x4 oa[4];
  #pragma unroll
  for(int m=0;m<4;m++) oa[m] = (f32x4){0.f,0.f,0.f,0.f};
  float lrun = 0.f, dnr = 0.f;

  const uint32_t vaddr_base = (uint32_t)(uintptr_t)(&VtB[0][0]) + (uint32_t)(l*8);

  for(int kt=0; kt<8; kt++){
    if(kt < 7){
      #pragma unroll
      for(int c=0;c<2;c++){
        const int ci = w*2 + c;
        gl_lds16(Kb + (size_t)((kt+1)*64 + ci*8 + lr3)*gstride + gbase + c8s*8,
                 KsB[(kt+1)&1] + ci*1024);
        gl_lds16(Vb + (size_t)((kt+1)*64 + vs[c])*gstride + gbase + vd[c],
                 VtB[(kt+1)&1] + w*2048 + c*1024);
      }
    }
    const char* Kc = KsB[kt&1];
    const float* kkt = &kkL[kt*64];
    const float* lmt = &lamL[kt*64];

    // ---- scores S^T = K * Q^T ----
    f32x4 st[4];
    #pragma unroll
    for(int t=0;t<4;t++){
      const bf16x8 ka0 = *(const bf16x8*)(Kc + (t*16+lr)*128 + ((g<<4) ^ swq));
      const bf16x8 ka1 = *(const bf16x8*)(Kc + (t*16+lr)*128 + (((4+g)<<4) ^ swq));
      f32x4 c0 = (f32x4){0.f,0.f,0.f,0.f};
      c0 = __builtin_amdgcn_mfma_f32_16x16x32_bf16(ka0, qf0, c0, 0,0,0);
      c0 = __builtin_amdgcn_mfma_f32_16x16x32_bf16(ka1, qf1, c0, 0,0,0);
      st[t] = c0;
    }

    // ---- transform: p = exp(score) directly (all scores <= 0) ----
    uint32_t pbw[8];
    {
      float ls = 0.f, dl = 0.f;
      #pragma unroll
      for(int t=0;t<4;t++){
        const f32x4 kkv = *(const f32x4*)(kkt + t*16 + g*4);
        float p[4];
        #pragma unroll
        for(int r=0;r<4;r++){
          const float qk = st[t][r], kk = kkv[r];
          const float a = qq + kk;
          if(hyp){
            const float u = fmaxf(fmaf(-2.f, qk, a), 0.f);
            const float v = fmaxf(fmaf(qq, kk, fmaf(-2.f, qk, 1.f)), EPSF);
            const float wz = __builtin_amdgcn_sqrtf(u*v);
            const float den = (u + v) + 2.f*wz;
            float ratio = (v - u) * __builtin_amdgcn_rcpf(den);
            ratio = fmaxf(ratio, 5.9604645e-8f);   // -> p_min = 0.125
            p[r] = __builtin_amdgcn_exp2f(0.125f * __builtin_amdgcn_logf(ratio));
          } else {
            const float d2 = fmaxf(fmaf(-2.f, qk, a), 0.f) + 1e-12f;
            p[r] = __builtin_amdgcn_exp2f(-0.18033688f * __builtin_amdgcn_sqrtf(d2));
          }
        }
        ls += (p[0]+p[1])+(p[2]+p[3]);
        if(hyp){
          const f32x4 lv = *(const f32x4*)(lmt + t*16 + g*4);
          dl += p[0]*(lv[0]-1.f) + p[1]*(lv[1]-1.f) + p[2]*(lv[2]-1.f) + p[3]*(lv[3]-1.f);
        }
        pbw[t*2]   = cvtpk(p[0], p[1]);
        pbw[t*2+1] = cvtpk(p[2], p[3]);
      }
      ls += __shfl_xor(ls,16); ls += __shfl_xor(ls,32);
      lrun += ls;
      if(hyp){
        dl += __shfl_xor(dl,16); dl += __shfl_xor(dl,32);
        dnr += dl;
      }
    }

    // ---- PV: O^T += V^T * P^T ; V via ds_read_b64_tr_b16, P from registers ----
    const uint32_t va_kt = vaddr_base + (uint32_t)((kt&1)*8192);
    {
      u32x2 r00=trrd<0>(va_kt),    r01=trrd<512>(va_kt);
      u32x2 r10=trrd<2048>(va_kt), r11=trrd<2560>(va_kt);
      u32x2 r20=trrd<4096>(va_kt), r21=trrd<4608>(va_kt);
      u32x2 r30=trrd<6144>(va_kt), r31=trrd<6656>(va_kt);
      asm volatile("s_waitcnt lgkmcnt(0)" ::: "memory");
      __builtin_amdgcn_sched_barrier(0);
      bf16x8 pb0;
      { union{uint32_t u[4]; bf16x8 v;} c;
        c.u[0]=pbw[0]; c.u[1]=pbw[1]; c.u[2]=pbw[2]; c.u[3]=pbw[3]; pb0=c.v; }
      __builtin_amdgcn_s_setprio(1);
      oa[0] = __builtin_amdgcn_mfma_f32_16x16x32_bf16(vcomb(r00,r01), pb0, oa[0], 0,0,0);
      oa[1] = __builtin_amdgcn_mfma_f32_16x16x32_bf16(vcomb(r10,r11), pb0, oa[1], 0,0,0);
      oa[2] = __builtin_amdgcn_mfma_f32_16x16x32_bf16(vcomb(r20,r21), pb0, oa[2], 0,0,0);
      oa[3] = __builtin_amdgcn_mfma_f32_16x16x32_bf16(vcomb(r30,r31), pb0, oa[3], 0,0,0);
      __builtin_amdgcn_s_setprio(0);
    }
    {
      u32x2 r00=trrd<1024>(va_kt), r01=trrd<1536>(va_kt);
      u32x2 r10=trrd<3072>(va_kt), r11=trrd<3584>(va_kt);
      u32x2 r20=trrd<5120>(va_kt), r21=trrd<5632>(va_kt);
      u32x2 r30=trrd<7168>(va_kt), r31=trrd<7680>(va_kt);
      asm volatile("s_waitcnt lgkmcnt(0)" ::: "memory");
      __builtin_amdgcn_sched_barrier(0);
      bf16x8 pb0;
      { union{uint32_t u[4]; bf16x8 v;} c;
        c.u[0]=pbw[4]; c.u[1]=pbw[5]; c.u[2]=pbw[6]; c.u[3]=pbw[7]; pb0=c.v; }
      __builtin_amdgcn_s_setprio(1);
      oa[0] = __builtin_amdgcn_mfma_f32_16x16x32_bf16(vcomb(r00,r01), pb0, oa[0], 0,0,0);
      oa[1] = __builtin_amdgcn_mfma_f32_16x16x32_bf16(vcomb(r10,r11), pb0, oa[1], 0,0,0);
      oa[2] = __builtin_amdgcn_mfma_f32_16x16x32_bf16(vcomb(r20,r21), pb0, oa[2], 0,0,0);
      oa[3] = __builtin_amdgcn_mfma_f32_16x16x32_bf16(vcomb(r30,r31), pb0, oa[3], 0,0,0);
      __builtin_amdgcn_s_setprio(0);
    }
    __syncthreads();   // one barrier per kt: staging drained, buffers swap
  }

  // ---- epilogue: restage via LDS overlay (on K dbuf), coalesced store ----
  char* OTB = (char*)KsB;
  float scale;
  {
    const float invl = 1.f/lrun;
    if(hyp){
      const float dn = fmaxf(dnr*invl, EPSF);
      scale = invl/dn;
    } else scale = invl;
  }
  #pragma unroll
  for(int m=0;m<4;m++){
    f32x4 vv;
    vv[0]=oa[m][0]*scale; vv[1]=oa[m][1]*scale;
    vv[2]=oa[m][2]*scale; vv[3]=oa[m][3]*scale;
    *(f32x4*)(OTB + w*4096 + lr*256 + ((m*64 + g*16) ^ ((lr&7)<<4))) = vv;
  }
  __syncthreads();
  {
    const int row = tid >> 2, cw = tid & 3;
    const int wsrc = row >> 4, ql = row & 15;
    float vals[16];
    #pragma unroll
    for(int ii=0;ii<4;ii++)
      *(f32x4*)&vals[ii*4] = *(const f32x4*)(OTB + wsrc*4096 + ql*256 + ((cw*64 + ii*16) ^ ((ql&7)<<4)));
    const size_t go = (size_t)(q0 + row)*gstride + gbase + cw*16;
    *(uint4*)(outB + go)     = pack8(vals);
    *(uint4*)(outB + go + 8) = pack8(vals+8);
  }
}

// =====================================================================
extern "C" void kernel_launch(void* const* d_in, const int* in_sizes, int n_in,
                              void* d_out, int out_size, void* d_ws, size_t ws_size,
                              hipStream_t stream)
{
  (void)in_sizes; (void)n_in; (void)out_size; (void)ws_size;
  const float* x    = (const float*)d_in[0];
  const float* ln1g = (const float*)d_in[1];
  const float* ln1b = (const float*)d_in[2];
  const float* ln2g = (const float*)d_in[3];
  const float* ln2b = (const float*)d_in[4];
  const float* Wq = (const float*)d_in[5];
  const float* bq = (const float*)d_in[6];
  const float* Wk = (const float*)d_in[7];
  const float* bk = (const float*)d_in[8];
  const float* Wv = (const float*)d_in[9];
  const float* bv = (const float*)d_in[10];
  const float* Wo = (const float*)d_in[11];
  const float* bo = (const float*)d_in[12];
  const float* W1 = (const float*)d_in[13];
  const float* b1 = (const float*)d_in[14];
  const float* W2 = (const float*)d_in[15];
  const float* b2 = (const float*)d_in[16];
  float* out = (float*)d_out;
  const float* x1 = x + (size_t)R_*E_;

  char* ws = (char*)d_ws;
  uint16_t* HB   = (uint16_t*)(ws);                         // 16MB [16384][512] bf16
  uint16_t* F1B  = (uint16_t*)(ws + ((size_t)16<<20));      // 64MB [16384][2048] (aliases QKV/OB)
  uint16_t* QKV0 = (uint16_t*)(ws + ((size_t)16<<20));      // 24MB [3][8192][512]
  uint16_t* QKV1 = (uint16_t*)(ws + ((size_t)40<<20));      // 24MB
  uint16_t* OB   = (uint16_t*)(ws + ((size_t)64<<20));      // 16MB [16384][512]
  float*    X2   = (float*)   (ws + ((size_t)80<<20));      // 32MB fp32 [16384][512] (e0,e1)
  float*    X2e1 = X2 + (size_t)R_*E_;
  uint16_t* WB   = (uint16_t*)(ws + ((size_t)112<<20));     // 12MB (both experts)
  char*     aux  = ws + ((size_t)124<<20);
  float*    YV   = (float*)(aux);                           // expmap'd biases (~19KB)
  float*    NH   = (float*)(aux + (32<<10));
  float*    NO   = NH + R_;
  float*    N3   = NO + R_;
  float*    N4   = N3 + R_;
  float*    qn0  = (float*)(aux + (256<<10));
  float*    kn0  = qn0 + 65536;
  float*    qn1  = kn0 + 65536;
  float*    kn1  = qn1 + 65536;
  float*    lam1 = kn1 + 65536;

  uint16_t* WBe = WB + 3145728;

  // ---- weights + biases (both experts) ----
  cvt_all<<<6144,256,0,stream>>>(Wq,Wk,Wv,Wo,W1,W2, WB);
  expmap_all<<<6,256,0,stream>>>(bq,bk,bv,bo,b1,b2, YV);

  // ---- LN1 both experts ----
  lnfuseW<<<4096,256,0,stream>>>(x, ln1g, ln1b, HB, NH, 0);

  // ---- fused QKV GEMM: e0 -> QKV0 (+bias), e1 -> QKV1 raw ----
  gemmF<<<dim3(12,128),256,0,stream>>>(HB, WB, WBe, R_, 1536, 512, 6, 7,
                                       bq, bk, bv, nullptr, nullptr, QKV0, QKV1);
  qk_norms<<<2048,256,0,stream>>>(QKV0, QKV0+4194304, qn0, kn0);
  man_epi_qkvW<<<dim3(2048,3),256,0,stream>>>(QKV1, NH, YV, QKV1, qn1, kn1, lam1);

  // ---- fused attention (2048 blocks: 1024 euclid + 1024 hyp) ----
  attnF2<<<2048,256,0,stream>>>(QKV0, QKV1, qn0, kn0, qn1, kn1, lam1, OB);
  o_finishW<<<2048,256,0,stream>>>(OB + (size_t)R_*E_, OB + (size_t)R_*E_, NO);

  // ---- fused projection GEMM: e0 -> X2 (+bias+res x), e1 raw -> HB ----
  gemmF<<<dim3(4,128),256,0,stream>>>(OB, WB+786432, WBe+786432, R_, 512, 512, 2, 5,
                                      bo, nullptr, nullptr, x, X2, nullptr, HB);
  man_epiW<8><<<2048,256,0,stream>>>(HB, NO, YV+1584, nullptr, nullptr, x1, X2e1, 0);

  // ---- LN2 both experts ----
  lnfuseW<<<4096,256,0,stream>>>(X2, ln2g, ln2b, HB, N3, 1);

  // ---- fused FFN1: e0 relu+bias, e1 raw (M=16384, N=2048) ----
  gemmF<<<dim3(16,128),256,0,stream>>>(HB, WB+1048576, WBe+1048576, R_, 2048, 512, 3, 5,
                                       b1, nullptr, nullptr, nullptr, nullptr,
                                       F1B, F1B + (size_t)R_*FFN_);
  man_epiW<32><<<2048,256,0,stream>>>(F1B + (size_t)R_*FFN_, N3, YV+2112,
                                      F1B + (size_t)R_*FFN_, N4, nullptr, nullptr, 1);

  // ---- fused FFN2: e0 relu+bias+res -> out, e1 raw -> HB (M=16384, K=2048) ----
  gemmF<<<dim3(4,128),256,0,stream>>>(F1B, WB+2097152, WBe+2097152, R_, 512, 2048, 4, 5,
                                      b2, nullptr, nullptr, X2, out, nullptr, HB);
  man_epiW<8><<<2048,256,0,stream>>>(HB, N4, YV+4176, nullptr, nullptr,
                                     X2e1, out + (size_t)R_*E_, 1|8);
}

// Round 10
// 373.610 us; speedup vs baseline: 1.3920x; 1.0542x over previous
//
#include <hip/hip_runtime.h>
#include <cstdint>
#include <cstddef>

#define S_ 512
#define B_ 16
#define H_ 8
#define D_ 64
#define E_ 512
#define FFN_ 2048
#define R_ (S_*B_)          // 8192 rows per expert
#define EPSF 1e-6f
#define PROJ_M 0.99999f     // 1 - 1e-5

typedef __attribute__((ext_vector_type(8))) short bf16x8;
typedef __attribute__((ext_vector_type(4))) float f32x4;
typedef __attribute__((ext_vector_type(2))) unsigned int u32x2;

// ---------- helpers ----------
__device__ __forceinline__ float bf2f(uint32_t u){
  union{uint32_t i; float f;} c; c.i = u<<16; return c.f;
}
__device__ __forceinline__ uint16_t f2bf(float f){
  union{float f; uint32_t i;} c; c.f = f;
  return (uint16_t)((c.i + 0x7FFFu + ((c.i>>16)&1u))>>16);
}
__device__ __forceinline__ void unpack8(uint4 u, float* f){
  f[0]=bf2f(u.x&0xFFFFu); f[1]=bf2f(u.x>>16);
  f[2]=bf2f(u.y&0xFFFFu); f[3]=bf2f(u.y>>16);
  f[4]=bf2f(u.z&0xFFFFu); f[5]=bf2f(u.z>>16);
  f[6]=bf2f(u.w&0xFFFFu); f[7]=bf2f(u.w>>16);
}
__device__ __forceinline__ uint4 pack8(const float* f){
  uint4 u;
  u.x = (uint32_t)f2bf(f[0]) | ((uint32_t)f2bf(f[1])<<16);
  u.y = (uint32_t)f2bf(f[2]) | ((uint32_t)f2bf(f[3])<<16);
  u.z = (uint32_t)f2bf(f[4]) | ((uint32_t)f2bf(f[5])<<16);
  u.w = (uint32_t)f2bf(f[6]) | ((uint32_t)f2bf(f[7])<<16);
  return u;
}
__device__ __forceinline__ float artanh_c(float x){
  return (x >= 0.99999994f) ? 8.4056215f : atanhf(x);
}
__device__ __forceinline__ float wave_sum(float x){
  #pragma unroll
  for(int o=32;o>=1;o>>=1) x += __shfl_xor(x,o);
  return x;
}
__device__ __forceinline__ float g8sum(float x){
  x += __shfl_xor(x,1); x += __shfl_xor(x,2); x += __shfl_xor(x,4);
  return x;
}
__device__ __forceinline__ float block_sum(float x, float* sb){
  x = wave_sum(x);
  const int w = threadIdx.x >> 6;
  __syncthreads();
  if((threadIdx.x & 63)==0) sb[w] = x;
  __syncthreads();
  return sb[0]+sb[1]+sb[2]+sb[3];
}
// async global->LDS, 16B per lane; LDS dest = wave-uniform base + lane*16
__device__ __forceinline__ void gl_lds16(const void* g, void* l){
  __builtin_amdgcn_global_load_lds(
    (const __attribute__((address_space(1))) void*)(uintptr_t)g,
    (__attribute__((address_space(3))) void*)(uint32_t)(uintptr_t)l, 16, 0, 0);
}
__device__ __forceinline__ uint32_t cvtpk(float a, float b){
  uint32_t r;
  asm("v_cvt_pk_bf16_f32 %0, %1, %2" : "=v"(r) : "v"(a), "v"(b));
  return r;
}
template<int OFF>
__device__ __forceinline__ u32x2 trrd(uint32_t addr){
  u32x2 r;
  asm volatile("ds_read_b64_tr_b16 %0, %1 offset:%2" : "=v"(r) : "v"(addr), "n"(OFF));
  return r;
}
__device__ __forceinline__ bf16x8 vcomb(u32x2 a, u32x2 b){
  union{ uint32_t u[4]; bf16x8 v; } c;
  c.u[0]=a[0]; c.u[1]=a[1]; c.u[2]=b[0]; c.u[3]=b[1];
  return c.v;
}

// ---------- all weights fp32 -> bf16 (both experts), one launch ----------
__global__ __launch_bounds__(256) void cvt_all(
  const float* __restrict__ Wq, const float* __restrict__ Wk,
  const float* __restrict__ Wv, const float* __restrict__ Wo,
  const float* __restrict__ W1, const float* __restrict__ W2,
  uint16_t* __restrict__ dst)
{
  int i4 = blockIdx.x*256 + threadIdx.x;   // 4-elem units, total 1572864
  int e = 0;
  if(i4 >= 786432){ e = 1; i4 -= 786432; }
  const int r = i4;
  const float* s;
  if(r < 65536)        s = Wq + (size_t)(r)*4        + (size_t)e*262144;
  else if(r < 131072)  s = Wk + (size_t)(r-65536)*4  + (size_t)e*262144;
  else if(r < 196608)  s = Wv + (size_t)(r-131072)*4 + (size_t)e*262144;
  else if(r < 262144)  s = Wo + (size_t)(r-196608)*4 + (size_t)e*262144;
  else if(r < 524288)  s = W1 + (size_t)(r-262144)*4 + (size_t)e*1048576;
  else                 s = W2 + (size_t)(r-524288)*4 + (size_t)e*1048576;
  const float4 f = *(const float4*)s;
  uint2 o;
  o.x = (uint32_t)f2bf(f.x) | ((uint32_t)f2bf(f.y)<<16);
  o.y = (uint32_t)f2bf(f.z) | ((uint32_t)f2bf(f.w)<<16);
  *(uint2*)(dst + (size_t)e*3145728 + (size_t)r*4) = o;
}

// ---------- expmap0 of all 6 expert-1 biases (16B-aligned 528-float strides) ----------
__global__ __launch_bounds__(256) void expmap_all(
  const float* __restrict__ bq, const float* __restrict__ bk,
  const float* __restrict__ bv, const float* __restrict__ bo,
  const float* __restrict__ b1, const float* __restrict__ b2,
  float* __restrict__ YV)
{
  __shared__ float sb[4];
  const int id = blockIdx.x, t = threadIdx.x;
  const float* src; float* dst; int C;
  if(id==0){ src=bq+E_;   dst=YV+0;    C=E_; }
  else if(id==1){ src=bk+E_;   dst=YV+528;  C=E_; }
  else if(id==2){ src=bv+E_;   dst=YV+1056; C=E_; }
  else if(id==3){ src=bo+E_;   dst=YV+1584; C=E_; }
  else if(id==4){ src=b1+FFN_; dst=YV+2112; C=FFN_; }
  else          { src=b2+E_;   dst=YV+4176; C=E_; }
  const int npc = C >> 8;
  float v[8]; float s2 = 0.f;
  for(int i=0;i<npc;i++){ v[i] = src[t+256*i]; s2 += v[i]*v[i]; }
  s2 = block_sum(s2, sb);
  const float n = sqrtf(s2 + 1e-15f);
  const float th = tanhf(n);
  const float sc = th/n;
  for(int i=0;i<npc;i++) dst[t+256*i] = v[i]*sc;
  if(t==0) dst[C] = th*th;
}

// ---------- fused LN both experts, WAVE-PER-ROW (no barriers) ----------
__global__ __launch_bounds__(256) void lnfuseW(const float* __restrict__ x,
  const float* __restrict__ g, const float* __restrict__ b,
  uint16_t* __restrict__ out, float* __restrict__ nout, int do_projx)
{
  const int row = blockIdx.x*4 + (threadIdx.x>>6);
  const int l = threadIdx.x & 63;
  const size_t base = (size_t)row*E_ + l*8;
  const int hyp = (row >= R_);
  const float* gg = g + (hyp? E_ : 0);
  const float* bb = b + (hyp? E_ : 0);
  float v[8];
  *(float4*)(v)   = *(const float4*)(x + base);
  *(float4*)(v+4) = *(const float4*)(x + base + 4);
  float s = 0.f;
  #pragma unroll
  for(int i=0;i<8;i++) s += v[i];
  const float mu = wave_sum(s) * (1.f/E_);
  float q = 0.f;
  #pragma unroll
  for(int i=0;i<8;i++){ v[i] -= mu; q += v[i]*v[i]; }
  const float var = wave_sum(q) * (1.f/E_);
  const float rs = 1.f/sqrtf(var + 1e-5f);
  float gv[8], bvv[8];
  *(float4*)(gv)    = *(const float4*)(gg + l*8);
  *(float4*)(gv+4)  = *(const float4*)(gg + l*8 + 4);
  *(float4*)(bvv)   = *(const float4*)(bb + l*8);
  *(float4*)(bvv+4) = *(const float4*)(bb + l*8 + 4);
  float t[8];
  #pragma unroll
  for(int i=0;i<8;i++) t[i] = v[i]*rs*gv[i] + bvv[i];
  if(hyp){
    float n = 0.f;
    #pragma unroll
    for(int i=0;i<8;i++) n += t[i]*t[i];
    n = wave_sum(n);
    const float n2 = sqrtf(n + 1e-15f);
    const float nh = tanhf(n2);
    float scl = nh/n2;
    float nrm = nh;
    if(do_projx && nrm > PROJ_M){ scl *= PROJ_M/nrm; nrm = PROJ_M; }
    #pragma unroll
    for(int i=0;i<8;i++) t[i] *= scl;
    if(l==0) nout[row - R_] = nrm;
  }
  *(uint4*)(out + base) = pack8(t);
}

// ---------- per-head squared norms of euclid Q,K (layout [b*8+h][s]) ----------
__global__ __launch_bounds__(256) void qk_norms(
  const uint16_t* __restrict__ Qb, const uint16_t* __restrict__ Kb,
  float* __restrict__ qn, float* __restrict__ kn)
{
  const int w = threadIdx.x >> 6, l = threadIdx.x & 63;
  const int row = blockIdx.x*4 + w;
  const int s = row >> 4, b = row & 15;
  const size_t base = (size_t)row*E_ + l*8;
  {
    uint4 u = *(const uint4*)(Qb + base);
    float f[8]; unpack8(u, f);
    float ss = 0.f;
    #pragma unroll
    for(int i=0;i<8;i++) ss += f[i]*f[i];
    ss = g8sum(ss);
    if((l&7)==0) qn[((b<<3) + (l>>3))*512 + s] = ss;
  }
  {
    uint4 u = *(const uint4*)(Kb + base);
    float f[8]; unpack8(u, f);
    float ss = 0.f;
    #pragma unroll
    for(int i=0;i<8;i++) ss += f[i]*f[i];
    ss = g8sum(ss);
    if((l&7)==0) kn[((b<<3) + (l>>3))*512 + s] = ss;
  }
}

// ---------- man_linear epilogue, WAVE-PER-ROW. EPL = C/64. flags: 1 relu; 8 projx-mid ----------
template<int EPL>
__global__ __launch_bounds__(256) void man_epiW(
  const uint16_t* __restrict__ mxb, const float* __restrict__ nxbuf,
  const float* __restrict__ y, uint16_t* __restrict__ outb,
  float* __restrict__ nout,
  const float* __restrict__ midres, float* __restrict__ midout, int flags)
{
  constexpr int C = EPL*64;
  const int row = blockIdx.x*4 + (threadIdx.x>>6);
  const int l = threadIdx.x & 63;
  const size_t base = (size_t)row*C + l*EPL;
  float v[EPL], yv[EPL];
  #pragma unroll
  for(int i=0;i<EPL/8;i++){
    uint4 u = *(const uint4*)(mxb + base + i*8);
    unpack8(u, v + i*8);
  }
  #pragma unroll
  for(int i=0;i<EPL/4;i++)
    *(float4*)(yv + i*4) = *(const float4*)(y + l*EPL + i*4);
  float s2 = 0.f;
  #pragma unroll
  for(int i=0;i<EPL;i++) s2 += v[i]*v[i];
  s2 = wave_sum(s2);
  const float nmx = sqrtf(s2 + 1e-15f);
  const float nx  = nxbuf[row];
  const float sc  = tanhf(nmx/nx * artanh_c(nx));
  const bool ok   = (nmx > 1e-7f);
  const float fmul = ok ? (sc/nmx) : 0.f;
  const float x2   = ok ? sc*sc : 0.f;
  float xy = 0.f;
  #pragma unroll
  for(int i=0;i<EPL;i++){ v[i] *= fmul; xy += v[i]*yv[i]; }
  xy = wave_sum(xy);
  const float y2 = y[C];
  const float aa = 1.f + 2.f*xy + y2;
  const float bb = 1.f - x2;
  const float iden = 1.f/fmaxf(1.f + 2.f*xy + x2*y2, EPSF);
  const float num2 = aa*aa*x2 + 2.f*aa*bb*xy + bb*bb*y2;
  const float nz = sqrtf(num2*iden*iden + 1e-15f);
  const float ps = (nz > PROJ_M) ? (PROJ_M/nz) : 1.f;
  float nfin = (nz > PROJ_M) ? PROJ_M : nz;
  #pragma unroll
  for(int i=0;i<EPL;i++) v[i] = (aa*v[i] + bb*yv[i]) * iden * ps;
  if(flags & 1){
    float rsu = 0.f;
    #pragma unroll
    for(int i=0;i<EPL;i++){ v[i] = fmaxf(v[i], 0.f); rsu += v[i]*v[i]; }
    rsu = wave_sum(rsu);
    nfin = sqrtf(rsu + 1e-15f);
  }
  if(midres){
    float bv2[EPL];
    #pragma unroll
    for(int i=0;i<EPL/4;i++)
      *(float4*)(bv2 + i*4) = *(const float4*)(midres + base + i*4);
    float pb = 0.f, pab = 0.f;
    #pragma unroll
    for(int i=0;i<EPL;i++){ pb += bv2[i]*bv2[i]; pab += v[i]*bv2[i]; }
    const float sa  = nfin*nfin;
    const float sbb = wave_sum(pb);
    const float sab = wave_sum(pab);
    const float l1 = 2.f/fmaxf(1.f - sa,  EPSF);
    const float l2 = 2.f/fmaxf(1.f - sbb, EPSF);
    const float idn = 1.f/fmaxf(l1 + l2 - 2.f, EPSF);
    const float nt2 = (l1*l1*sa + 2.f*l1*l2*sab + l2*l2*sbb)*idn*idn;
    const float nt = sqrtf(nt2 + 1e-15f);
    const float sfin = tanhf(0.5f*artanh_c(nt));
    float scm = sfin/nt;
    if((flags & 8) && sfin > PROJ_M) scm *= PROJ_M/sfin;
    #pragma unroll
    for(int i=0;i<EPL;i++) midout[base + i] = (v[i]*l1 + bv2[i]*l2)*idn*scm;
  } else {
    #pragma unroll
    for(int i=0;i<EPL/8;i++)
      *(uint4*)(outb + base + i*8) = pack8(v + i*8);
    if(nout && l==0) nout[row] = nfin;
  }
}

// ---------- fused hyp q/k/v man_linear epilogue, WAVE-PER-ROW (in-place) ----------
__global__ __launch_bounds__(256) void man_epi_qkvW(
  const uint16_t* __restrict__ mxb, const float* __restrict__ nxbuf,
  const float* __restrict__ YV, uint16_t* __restrict__ qkv,
  float* __restrict__ qnG, float* __restrict__ knG, float* __restrict__ lamG)
{
  const int sel = blockIdx.y;
  const int row = blockIdx.x*4 + (threadIdx.x>>6);
  const int l = threadIdx.x & 63;
  const float* y = YV + sel*528;
  const size_t base = (size_t)sel*4194304 + (size_t)row*512 + l*8;
  float v[8], yv[8];
  {
    uint4 u = *(const uint4*)(mxb + base);
    unpack8(u, v);
  }
  *(float4*)(yv)   = *(const float4*)(y + l*8);
  *(float4*)(yv+4) = *(const float4*)(y + l*8 + 4);
  float s2 = 0.f;
  #pragma unroll
  for(int i=0;i<8;i++) s2 += v[i]*v[i];
  s2 = wave_sum(s2);
  const float nmx = sqrtf(s2 + 1e-15f);
  const float nx  = nxbuf[row];
  const float sc  = tanhf(nmx/nx * artanh_c(nx));
  const bool ok   = (nmx > 1e-7f);
  const float fmul = ok ? (sc/nmx) : 0.f;
  const float x2   = ok ? sc*sc : 0.f;
  float xy = 0.f;
  #pragma unroll
  for(int i=0;i<8;i++){ v[i] *= fmul; xy += v[i]*yv[i]; }
  xy = wave_sum(xy);
  const float y2 = y[512];
  const float aa = 1.f + 2.f*xy + y2;
  const float bb = 1.f - x2;
  const float iden = 1.f/fmaxf(1.f + 2.f*xy + x2*y2, EPSF);
  const float num2 = aa*aa*x2 + 2.f*aa*bb*xy + bb*bb*y2;
  const float nz = sqrtf(num2*iden*iden + 1e-15f);
  const float ps = (nz > PROJ_M) ? (PROJ_M/nz) : 1.f;
  #pragma unroll
  for(int i=0;i<8;i++) v[i] = (aa*v[i] + bb*yv[i]) * iden * ps;
  // per-head projx (+ lambda): head = l>>3 (8 lanes x 8 elems = 64)
  float hs = 0.f;
  #pragma unroll
  for(int i=0;i<8;i++) hs += v[i]*v[i];
  hs = g8sum(hs);
  float nh = sqrtf(hs + 1e-15f);
  float phs = 1.f;
  if(nh > PROJ_M){ phs = PROJ_M/nh; nh = PROJ_M; }
  #pragma unroll
  for(int i=0;i<8;i++) v[i] *= phs;
  const float nh2 = nh*nh;
  const float lam = 2.f/fmaxf(1.f - nh2, EPSF);
  if(sel==2){
    #pragma unroll
    for(int i=0;i<8;i++) v[i] *= lam;
  }
  if((l & 7) == 0){
    const int s = row >> 4, b2 = row & 15;
    const int idx = ((b2<<3) + (l>>3))*512 + s;
    if(sel==0) qnG[idx] = nh2;
    else if(sel==1) knG[idx] = nh2;
    else lamG[idx] = lam;
  }
  *(uint4*)(qkv + base) = pack8(v);
}

// ---------- hyp attention-output finish, WAVE-PER-ROW (in-place) ----------
__global__ __launch_bounds__(256) void o_finishW(const uint16_t* __restrict__ op,
  uint16_t* __restrict__ outb, float* __restrict__ nout)
{
  const int row = blockIdx.x*4 + (threadIdx.x>>6);
  const int l = threadIdx.x & 63;
  const size_t base = (size_t)row*E_ + l*8;
  float v[8];
  {
    uint4 u = *(const uint4*)(op + base);
    unpack8(u, v);
  }
  float hs = 0.f;
  #pragma unroll
  for(int i=0;i<8;i++) hs += v[i]*v[i];
  hs = g8sum(hs);
  const float ns = sqrtf(hs + 1e-15f);
  const float tt = tanhf(0.5f*artanh_c(ns));
  float scv = tt/ns;
  float sn = tt;
  if(sn > PROJ_M){ scv *= PROJ_M/sn; sn = PROJ_M; }
  float tot = 0.f;
  #pragma unroll
  for(int i=0;i<8;i++){ v[i] *= scv; tot += v[i]*v[i]; }
  tot = wave_sum(tot);
  const float n = sqrtf(tot + 1e-15f);
  float nf = n;
  if(n > PROJ_M){
    const float s = PROJ_M/n;
    #pragma unroll
    for(int i=0;i<8;i++) v[i] *= s;
    nf = PROJ_M;
  }
  *(uint4*)(outb + base) = pack8(v);
  if(l==0) nout[row] = nf;
}

// ---------- bf16 MFMA GEMM v2: BK=32 dbuf (32KB LDS), 4 blocks/CU,
// LDS-transposed vectorized epilogue. Expert-split by m-range, XCD-swizzled.
// modes: 2 +bias+res->outf(fp32); 3 relu+bias->outb; 4 relu+bias+res->outf;
//        5 raw->outb; 6 QKV-split +bias->outb; 7 QKV-split raw->outb
__global__ __launch_bounds__(256,4) void gemmF(
    const uint16_t* __restrict__ A,
    const uint16_t* __restrict__ Bw0, const uint16_t* __restrict__ Bw1,
    int msplit, int N, int K, int mode0, int mode1,
    const float* __restrict__ bQ, const float* __restrict__ bK,
    const float* __restrict__ bV, const float* __restrict__ res0,
    float* __restrict__ outf0,
    uint16_t* __restrict__ outb0, uint16_t* __restrict__ outb1)
{
  __shared__ __align__(16) char smem[33792];   // staging 32KB; epilogue overlay 64x132 f32
  const int gx = gridDim.x;
  int lid = blockIdx.x + gx*blockIdx.y;
  {
    const int nwg = gx*gridDim.y;           // all call sites have nwg % 8 == 0
    const int cpx = nwg >> 3;
    lid = (lid & 7)*cpx + (lid >> 3);       // bijective XCD-contiguous remap
  }
  const int m0 = (lid/gx)*128;
  const int n0 = (lid%gx)*128;
  const int e  = (m0 >= msplit);
  const uint16_t* Bw = e ? Bw1 : Bw0;
  uint16_t* ob = e ? outb1 : outb0;
  const int mode = e ? mode1 : mode0;
  const int mloc0 = m0 - (e ? msplit : 0);

  const int tid = threadIdx.x;
  const int l = tid & 63, w = tid >> 6;
  const int wm = w >> 1, wn = w & 1;
  const int lr = l & 15, g = l >> 4;

  // staging: lane l covers LDS row (l>>2), slot (l&3); global chunk pre-swizzled
  const int srow4 = l >> 2;
  const int schunk = ((l & 3) ^ ((l >> 3) & 3)) << 3;   // element offset
  const uint16_t* aS = A  + (size_t)(m0 + w*32 + srow4)*K + schunk;
  const uint16_t* bS = Bw + (size_t)(n0 + w*32 + srow4)*K + schunk;
  // read-side swizzle: slot = g ^ ((row>>1)&3); row%16 == lr
  const int posq = (g ^ ((lr >> 1) & 3)) << 4;

  f32x4 acc[4][4];
  #pragma unroll
  for(int i=0;i<4;i++)
    #pragma unroll
    for(int j=0;j<4;j++) acc[i][j] = (f32x4){0.f,0.f,0.f,0.f};

  const int nk = K >> 5;

#define STG(ks, b) { \
    const int k0_ = (ks) << 5; \
    char* ad_ = smem + (b)*8192 + w*2048; \
    char* bd_ = smem + 16384 + (b)*8192 + w*2048; \
    gl_lds16(aS + k0_,                 ad_); \
    gl_lds16(aS + (size_t)16*K + k0_,  ad_ + 1024); \
    gl_lds16(bS + k0_,                 bd_); \
    gl_lds16(bS + (size_t)16*K + k0_,  bd_ + 1024); \
  }

  STG(0, 0);
  for(int ks=0; ks<nk; ks++){
    __syncthreads();
    if(ks+1 < nk) STG(ks+1, (ks+1)&1);
    const char* Ac = smem + (ks&1)*8192;
    const char* Bc = smem + 16384 + (ks&1)*8192;
    bf16x8 av[4], bv[4];
    #pragma unroll
    for(int i=0;i<4;i++){
      av[i] = *(const bf16x8*)(Ac + (wm*64 + i*16 + lr)*64 + posq);
      bv[i] = *(const bf16x8*)(Bc + (wn*64 + i*16 + lr)*64 + posq);
    }
    #pragma unroll
    for(int i=0;i<4;i++)
      #pragma unroll
      for(int j=0;j<4;j++)
        acc[i][j] = __builtin_amdgcn_mfma_f32_16x16x32_bf16(av[i], bv[j], acc[i][j], 0,0,0);
  }
#undef STG

  // ---- epilogue: transpose 128x128 through LDS (two 64-row passes), vector stores ----
  float* Ep = (float*)smem;
  const int ecr = tid >> 2;            // 0..63  (compacted row)
  const int ecb = (tid & 3) * 32;      // col base
  // bias / output bases (mode 6/7: QKV scatter within [sel][row][512])
  const float* bptr = bQ;
  uint16_t* obase = ob;
  int ncol0 = n0;
  size_t ostride = (size_t)N;
  if(mode==6 || mode==7){
    const int sel = n0 >> 9;
    obase = ob + (size_t)sel*4194304;
    ncol0 = n0 & 511;
    ostride = 512;
    if(mode==6) bptr = (sel==0)? bQ : ((sel==1)? bK : bV);
  }
  #pragma unroll
  for(int p=0;p<2;p++){
    __syncthreads();
    #pragma unroll
    for(int i2=0;i2<2;i2++){
      const int i = p*2 + i2;
      const int cr = wm*32 + i2*16 + g*4;
      #pragma unroll
      for(int j=0;j<4;j++){
        const int col = wn*64 + j*16 + lr;
        Ep[(cr+0)*132 + col] = acc[i][j][0];
        Ep[(cr+1)*132 + col] = acc[i][j][1];
        Ep[(cr+2)*132 + col] = acc[i][j][2];
        Ep[(cr+3)*132 + col] = acc[i][j][3];
      }
    }
    __syncthreads();
    const int grow = mloc0 + (ecr & 31) + ((ecr >> 5) << 6) + p*32;
    const float* Er = Ep + ecr*132 + ecb;
    if(mode==2 || mode==4){
      #pragma unroll
      for(int k=0;k<8;k++){
        const int colg = n0 + ecb + k*4;
        float4 vv = *(const float4*)(Er + k*4);
        const float4 bb4 = *(const float4*)(bQ + colg);
        const size_t off = (size_t)grow*N + colg;
        const float4 rr4 = *(const float4*)(res0 + off);
        float4 o4;
        if(mode==2){
          o4.x = vv.x + bb4.x + rr4.x; o4.y = vv.y + bb4.y + rr4.y;
          o4.z = vv.z + bb4.z + rr4.z; o4.w = vv.w + bb4.w + rr4.w;
        } else {
          o4.x = fmaxf(vv.x + bb4.x, 0.f) + rr4.x; o4.y = fmaxf(vv.y + bb4.y, 0.f) + rr4.y;
          o4.z = fmaxf(vv.z + bb4.z, 0.f) + rr4.z; o4.w = fmaxf(vv.w + bb4.w, 0.f) + rr4.w;
        }
        *(float4*)(outf0 + off) = o4;
      }
    } else {
      #pragma unroll
      for(int k=0;k<4;k++){
        const int colact = ecb + k*8;
        float f[8];
        *(float4*)(f)   = *(const float4*)(Er + k*8);
        *(float4*)(f+4) = *(const float4*)(Er + k*8 + 4);
        if(mode==3 || mode==6){
          float bb8[8];
          *(float4*)(bb8)   = *(const float4*)(bptr + ncol0 + colact);
          *(float4*)(bb8+4) = *(const float4*)(bptr + ncol0 + colact + 4);
          if(mode==3){
            #pragma unroll
            for(int i=0;i<8;i++) f[i] = fmaxf(f[i] + bb8[i], 0.f);
          } else {
            #pragma unroll
            for(int i=0;i<8;i++) f[i] = f[i] + bb8[i];
          }
        }
        *(uint4*)(obase + (size_t)grow*ostride + ncol0 + colact) = pack8(f);
      }
    }
  }
}

// ---------- fused MFMA flash attention v4: 2048 blocks, one 64-row q-tile each ----------
__global__ __launch_bounds__(256,3) void attnF2(
  const uint16_t* __restrict__ QKV0, const uint16_t* __restrict__ QKV1,
  const float* __restrict__ qn0, const float* __restrict__ kn0,
  const float* __restrict__ qn1, const float* __restrict__ kn1,
  const float* __restrict__ lam1, uint16_t* __restrict__ OB)
{
  __shared__ __align__(16) char QsB[8192];      // [64][64] bf16 swz
  __shared__ __align__(16) char KsB[2][8192];   // dbuf K tile (epilogue overlay)
  __shared__ __align__(16) char VtB[2][8192];   // dbuf V, tr-subtiled
  __shared__ float kkL[512];
  __shared__ float lamL[512];

  const int tid = threadIdx.x;
  const int l = tid & 63, w = tid >> 6;
  const int lr = l & 15, g = l >> 4;
  const int lr3 = l >> 3, lc = l & 7;
  const int c8s = lc ^ lr3;
  const int swq = (lr & 7) << 4;
  // XCD swizzle over 2048 blocks; lid partitions: [expert][bh][qtile]
  int lid = blockIdx.x;
  lid = (lid & 7)*256 + (lid >> 3);
  const int hyp = lid >> 10;
  const int sub = lid & 1023;
  const int bh = sub >> 3;
  const int q0 = (sub & 7) * 64;
  const uint16_t* Qb = hyp ? QKV1 : QKV0;
  const uint16_t* Kb = Qb + 4194304;
  const uint16_t* Vb = Qb + 8388608;
  const float* qnG = hyp ? qn1 : qn0;
  const float* knG = hyp ? kn1 : kn0;
  uint16_t* outB = OB + (size_t)hyp*4194304;
  const size_t gstride = (size_t)B_*E_;
  const size_t gbase = (size_t)(bh>>3)*E_ + (size_t)(bh&7)*D_;

  // V-staging decode: chunk ci covers LDS elems [w*1024+ci*512+l*8, +8)
  int vs[2], vd[2];
  #pragma unroll
  for(int ci=0;ci<2;ci++){
    vs[ci] = (ci*8 + (l>>3))*4 + ((l>>1)&3);
    vd[ci] = w*16 + (l&1)*8;
  }

  // ---- prologue staging ----
  #pragma unroll
  for(int c=0;c<2;c++){
    const int ci = w*2 + c;
    gl_lds16(Qb + (size_t)(q0 + ci*8 + lr3)*gstride + gbase + c8s*8, QsB + ci*1024);
    gl_lds16(Kb + (size_t)(ci*8 + lr3)*gstride + gbase + c8s*8, KsB[0] + ci*1024);
    gl_lds16(Vb + (size_t)vs[c]*gstride + gbase + vd[c], VtB[0] + w*2048 + c*1024);
  }
  kkL[tid]       = knG[bh*512 + tid];
  kkL[tid + 256] = knG[bh*512 + 256 + tid];
  if(hyp){
    lamL[tid]       = lam1[bh*512 + tid];
    lamL[tid + 256] = lam1[bh*512 + 256 + tid];
  }
  __syncthreads();

  // hoist Q fragments + qq
  const int qrow = w*16 + lr;
  bf16x8 qf0, qf1;
  qf0 = *(const bf16x8*)(QsB + qrow*128 + ((g<<4) ^ swq));
  qf1 = *(const bf16x8*)(QsB + qrow*128 + (((4+g)<<4) ^ swq));
  const float qq = qnG[bh*512 + q0 + qrow];

  f32x4 oa[4];
  #pragma unroll
  for(int m=0;m<4;m++) oa[m] = (f32x4){0.f,0.f,0.f,0.f};
  float lrun = 0.f, dnr = 0.f;

  const uint32_t vaddr_base = (uint32_t)(uintptr_t)(&VtB[0][0]) + (uint32_t)(l*8);

  for(int kt=0; kt<8; kt++){
    if(kt < 7){
      #pragma unroll
      for(int c=0;c<2;c++){
        const int ci = w*2 + c;
        gl_lds16(Kb + (size_t)((kt+1)*64 + ci*8 + lr3)*gstride + gbase + c8s*8,
                 KsB[(kt+1)&1] + ci*1024);
        gl_lds16(Vb + (size_t)((kt+1)*64 + vs[c])*gstride + gbase + vd[c],
                 VtB[(kt+1)&1] + w*2048 + c*1024);
      }
    }
    const char* Kc = KsB[kt&1];
    const float* kkt = &kkL[kt*64];
    const float* lmt = &lamL[kt*64];

    // ---- scores S^T = K * Q^T ----
    f32x4 st[4];
    #pragma unroll
    for(int t=0;t<4;t++){
      const bf16x8 ka0 = *(const bf16x8*)(Kc + (t*16+lr)*128 + ((g<<4) ^ swq));
      const bf16x8 ka1 = *(const bf16x8*)(Kc + (t*16+lr)*128 + (((4+g)<<4) ^ swq));
      f32x4 c0 = (f32x4){0.f,0.f,0.f,0.f};
      c0 = __builtin_amdgcn_mfma_f32_16x16x32_bf16(ka0, qf0, c0, 0,0,0);
      c0 = __builtin_amdgcn_mfma_f32_16x16x32_bf16(ka1, qf1, c0, 0,0,0);
      st[t] = c0;
    }

    // ---- transform: p = exp(score) directly (all scores <= 0) ----
    uint32_t pbw[8];
    {
      float ls = 0.f, dl = 0.f;
      #pragma unroll
      for(int t=0;t<4;t++){
        const f32x4 kkv = *(const f32x4*)(kkt + t*16 + g*4);
        float p[4];
        #pragma unroll
        for(int r=0;r<4;r++){
          const float qk = st[t][r], kk = kkv[r];
          const float a = qq + kk;
          if(hyp){
            const float u = fmaxf(fmaf(-2.f, qk, a), 0.f);
            const float v = fmaxf(fmaf(qq, kk, fmaf(-2.f, qk, 1.f)), EPSF);
            const float wz = __builtin_amdgcn_sqrtf(u*v);
            const float den = (u + v) + 2.f*wz;
            float ratio = (v - u) * __builtin_amdgcn_rcpf(den);
            ratio = fmaxf(ratio, 5.9604645e-8f);   // -> p_min = 0.125
            p[r] = __builtin_amdgcn_exp2f(0.125f * __builtin_amdgcn_logf(ratio));
          } else {
            const float d2 = fmaxf(fmaf(-2.f, qk, a), 0.f) + 1e-12f;
            p[r] = __builtin_amdgcn_exp2f(-0.18033688f * __builtin_amdgcn_sqrtf(d2));
          }
        }
        ls += (p[0]+p[1])+(p[2]+p[3]);
        if(hyp){
          const f32x4 lv = *(const f32x4*)(lmt + t*16 + g*4);
          dl += p[0]*(lv[0]-1.f) + p[1]*(lv[1]-1.f) + p[2]*(lv[2]-1.f) + p[3]*(lv[3]-1.f);
        }
        pbw[t*2]   = cvtpk(p[0], p[1]);
        pbw[t*2+1] = cvtpk(p[2], p[3]);
      }
      ls += __shfl_xor(ls,16); ls += __shfl_xor(ls,32);
      lrun += ls;
      if(hyp){
        dl += __shfl_xor(dl,16); dl += __shfl_xor(dl,32);
        dnr += dl;
      }
    }

    // ---- PV: O^T += V^T * P^T ; V via ds_read_b64_tr_b16, P from registers ----
    const uint32_t va_kt = vaddr_base + (uint32_t)((kt&1)*8192);
    {
      u32x2 r00=trrd<0>(va_kt),    r01=trrd<512>(va_kt);
      u32x2 r10=trrd<2048>(va_kt), r11=trrd<2560>(va_kt);
      u32x2 r20=trrd<4096>(va_kt), r21=trrd<4608>(va_kt);
      u32x2 r30=trrd<6144>(va_kt), r31=trrd<6656>(va_kt);
      asm volatile("s_waitcnt lgkmcnt(0)" ::: "memory");
      __builtin_amdgcn_sched_barrier(0);
      bf16x8 pb0;
      { union{uint32_t u[4]; bf16x8 v;} c;
        c.u[0]=pbw[0]; c.u[1]=pbw[1]; c.u[2]=pbw[2]; c.u[3]=pbw[3]; pb0=c.v; }
      __builtin_amdgcn_s_setprio(1);
      oa[0] = __builtin_amdgcn_mfma_f32_16x16x32_bf16(vcomb(r00,r01), pb0, oa[0], 0,0,0);
      oa[1] = __builtin_amdgcn_mfma_f32_16x16x32_bf16(vcomb(r10,r11), pb0, oa[1], 0,0,0);
      oa[2] = __builtin_amdgcn_mfma_f32_16x16x32_bf16(vcomb(r20,r21), pb0, oa[2], 0,0,0);
      oa[3] = __builtin_amdgcn_mfma_f32_16x16x32_bf16(vcomb(r30,r31), pb0, oa[3], 0,0,0);
      __builtin_amdgcn_s_setprio(0);
    }
    {
      u32x2 r00=trrd<1024>(va_kt), r01=trrd<1536>(va_kt);
      u32x2 r10=trrd<3072>(va_kt), r11=trrd<3584>(va_kt);
      u32x2 r20=trrd<5120>(va_kt), r21=trrd<5632>(va_kt);
      u32x2 r30=trrd<7168>(va_kt), r31=trrd<7680>(va_kt);
      asm volatile("s_waitcnt lgkmcnt(0)" ::: "memory");
      __builtin_amdgcn_sched_barrier(0);
      bf16x8 pb0;
      { union{uint32_t u[4]; bf16x8 v;} c;
        c.u[0]=pbw[4]; c.u[1]=pbw[5]; c.u[2]=pbw[6]; c.u[3]=pbw[7]; pb0=c.v; }
      __builtin_amdgcn_s_setprio(1);
      oa[0] = __builtin_amdgcn_mfma_f32_16x16x32_bf16(vcomb(r00,r01), pb0, oa[0], 0,0,0);
      oa[1] = __builtin_amdgcn_mfma_f32_16x16x32_bf16(vcomb(r10,r11), pb0, oa[1], 0,0,0);
      oa[2] = __builtin_amdgcn_mfma_f32_16x16x32_bf16(vcomb(r20,r21), pb0, oa[2], 0,0,0);
      oa[3] = __builtin_amdgcn_mfma_f32_16x16x32_bf16(vcomb(r30,r31), pb0, oa[3], 0,0,0);
      __builtin_amdgcn_s_setprio(0);
    }
    __syncthreads();   // one barrier per kt: staging drained, buffers swap
  }

  // ---- epilogue: restage via LDS overlay (on K dbuf), coalesced store ----
  char* OTB = (char*)KsB;
  float scale;
  {
    const float invl = 1.f/lrun;
    if(hyp){
      const float dn = fmaxf(dnr*invl, EPSF);
      scale = invl/dn;
    } else scale = invl;
  }
  #pragma unroll
  for(int m=0;m<4;m++){
    f32x4 vv;
    vv[0]=oa[m][0]*scale; vv[1]=oa[m][1]*scale;
    vv[2]=oa[m][2]*scale; vv[3]=oa[m][3]*scale;
    *(f32x4*)(OTB + w*4096 + lr*256 + ((m*64 + g*16) ^ ((lr&7)<<4))) = vv;
  }
  __syncthreads();
  {
    const int row = tid >> 2, cw = tid & 3;
    const int wsrc = row >> 4, ql = row & 15;
    float vals[16];
    #pragma unroll
    for(int ii=0;ii<4;ii++)
      *(f32x4*)&vals[ii*4] = *(const f32x4*)(OTB + wsrc*4096 + ql*256 + ((cw*64 + ii*16) ^ ((ql&7)<<4)));
    const size_t go = (size_t)(q0 + row)*gstride + gbase + cw*16;
    *(uint4*)(outB + go)     = pack8(vals);
    *(uint4*)(outB + go + 8) = pack8(vals+8);
  }
}

// =====================================================================
extern "C" void kernel_launch(void* const* d_in, const int* in_sizes, int n_in,
                              void* d_out, int out_size, void* d_ws, size_t ws_size,
                              hipStream_t stream)
{
  (void)in_sizes; (void)n_in; (void)out_size; (void)ws_size;
  const float* x    = (const float*)d_in[0];
  const float* ln1g = (const float*)d_in[1];
  const float* ln1b = (const float*)d_in[2];
  const float* ln2g = (const float*)d_in[3];
  const float* ln2b = (const float*)d_in[4];
  const float* Wq = (const float*)d_in[5];
  const float* bq = (const float*)d_in[6];
  const float* Wk = (const float*)d_in[7];
  const float* bk = (const float*)d_in[8];
  const float* Wv = (const float*)d_in[9];
  const float* bv = (const float*)d_in[10];
  const float* Wo = (const float*)d_in[11];
  const float* bo = (const float*)d_in[12];
  const float* W1 = (const float*)d_in[13];
  const float* b1 = (const float*)d_in[14];
  const float* W2 = (const float*)d_in[15];
  const float* b2 = (const float*)d_in[16];
  float* out = (float*)d_out;
  const float* x1 = x + (size_t)R_*E_;

  char* ws = (char*)d_ws;
  uint16_t* HB   = (uint16_t*)(ws);                         // 16MB [16384][512] bf16
  uint16_t* F1B  = (uint16_t*)(ws + ((size_t)16<<20));      // 64MB [16384][2048] (aliases QKV/OB)
  uint16_t* QKV0 = (uint16_t*)(ws + ((size_t)16<<20));      // 24MB [3][8192][512]
  uint16_t* QKV1 = (uint16_t*)(ws + ((size_t)40<<20));      // 24MB
  uint16_t* OB   = (uint16_t*)(ws + ((size_t)64<<20));      // 16MB [16384][512]
  float*    X2   = (float*)   (ws + ((size_t)80<<20));      // 32MB fp32 [16384][512] (e0,e1)
  float*    X2e1 = X2 + (size_t)R_*E_;
  uint16_t* WB   = (uint16_t*)(ws + ((size_t)112<<20));     // 12MB (both experts)
  char*     aux  = ws + ((size_t)124<<20);
  float*    YV   = (float*)(aux);                           // expmap'd biases (~19KB)
  float*    NH   = (float*)(aux + (32<<10));
  float*    NO   = NH + R_;
  float*    N3   = NO + R_;
  float*    N4   = N3 + R_;
  float*    qn0  = (float*)(aux + (256<<10));
  float*    kn0  = qn0 + 65536;
  float*    qn1  = kn0 + 65536;
  float*    kn1  = qn1 + 65536;
  float*    lam1 = kn1 + 65536;

  uint16_t* WBe = WB + 3145728;

  // ---- weights + biases (both experts) ----
  cvt_all<<<6144,256,0,stream>>>(Wq,Wk,Wv,Wo,W1,W2, WB);
  expmap_all<<<6,256,0,stream>>>(bq,bk,bv,bo,b1,b2, YV);

  // ---- LN1 both experts ----
  lnfuseW<<<4096,256,0,stream>>>(x, ln1g, ln1b, HB, NH, 0);

  // ---- fused QKV GEMM: e0 -> QKV0 (+bias), e1 -> QKV1 raw ----
  gemmF<<<dim3(12,128),256,0,stream>>>(HB, WB, WBe, R_, 1536, 512, 6, 7,
                                       bq, bk, bv, nullptr, nullptr, QKV0, QKV1);
  qk_norms<<<2048,256,0,stream>>>(QKV0, QKV0+4194304, qn0, kn0);
  man_epi_qkvW<<<dim3(2048,3),256,0,stream>>>(QKV1, NH, YV, QKV1, qn1, kn1, lam1);

  // ---- fused attention (2048 blocks: 1024 euclid + 1024 hyp) ----
  attnF2<<<2048,256,0,stream>>>(QKV0, QKV1, qn0, kn0, qn1, kn1, lam1, OB);
  o_finishW<<<2048,256,0,stream>>>(OB + (size_t)R_*E_, OB + (size_t)R_*E_, NO);

  // ---- fused projection GEMM: e0 -> X2 (+bias+res x), e1 raw -> HB ----
  gemmF<<<dim3(4,128),256,0,stream>>>(OB, WB+786432, WBe+786432, R_, 512, 512, 2, 5,
                                      bo, nullptr, nullptr, x, X2, nullptr, HB);
  man_epiW<8><<<2048,256,0,stream>>>(HB, NO, YV+1584, nullptr, nullptr, x1, X2e1, 0);

  // ---- LN2 both experts ----
  lnfuseW<<<4096,256,0,stream>>>(X2, ln2g, ln2b, HB, N3, 1);

  // ---- fused FFN1: e0 relu+bias, e1 raw (M=16384, N=2048) ----
  gemmF<<<dim3(16,128),256,0,stream>>>(HB, WB+1048576, WBe+1048576, R_, 2048, 512, 3, 5,
                                       b1, nullptr, nullptr, nullptr, nullptr,
                                       F1B, F1B + (size_t)R_*FFN_);
  man_epiW<32><<<2048,256,0,stream>>>(F1B + (size_t)R_*FFN_, N3, YV+2112,
                                      F1B + (size_t)R_*FFN_, N4, nullptr, nullptr, 1);

  // ---- fused FFN2: e0 relu+bias+res -> out, e1 raw -> HB (M=16384, K=2048) ----
  gemmF<<<dim3(4,128),256,0,stream>>>(F1B, WB+2097152, WBe+2097152, R_, 512, 2048, 4, 5,
                                      b2, nullptr, nullptr, X2, out, nullptr, HB);
  man_epiW<8><<<2048,256,0,stream>>>(HB, N4, YV+4176, nullptr, nullptr,
                                     X2e1, out + (size_t)R_*E_, 1|8);
}